// Round 1
// baseline (760.451 us; speedup 1.0000x reference)
//
#include <hip/hip_runtime.h>
#include <math.h>

#define NB 2
#define NQ 8192
#define NL 8192
#define NC 128
#define NKN 8
#define NF 512
#define MQ (NB*NQ)   // 16384 rows total (both batches)

// ---------------------------------------------------------------------------
// Kernel 1: radius graph + top-8 nearest within RADIUS.
// 256 threads / block, 64 queries / block, 4 threads per query.
// kv_xyz staged through LDS in 4 passes of 2048 points (40KB LDS total).
// Each thread keeps a sorted top-8 in registers; 4 partial lists merged in LDS.
// ---------------------------------------------------------------------------
#define SWAP_STEP(da, db, ia, ib) if ((db) < (da)) { float _tf=(da); (da)=(db); (db)=_tf; int _ti=(ia); (ia)=(ib); (ib)=_ti; }

__global__ __launch_bounds__(256) void radius_topk_kernel(
    const float* __restrict__ qxyz, const float* __restrict__ kxyz,
    const unsigned char* __restrict__ pad, int* __restrict__ idxout)
{
    __shared__ float sx[2048*3];
    __shared__ float md[2048];
    __shared__ int   mi[2048];
    const int tid = threadIdx.x;
    const int q0  = blockIdx.x * 64;
    const int bat = q0 >> 13;          // q0 / 8192
    const int qq  = tid >> 2, tsub = tid & 3;
    const int gq  = q0 + qq;
    const float qx = qxyz[gq*3+0], qy = qxyz[gq*3+1], qz = qxyz[gq*3+2];
    const float R2 = (float)(0.4*0.4);

    float dk0=INFINITY,dk1=INFINITY,dk2=INFINITY,dk3=INFINITY,
          dk4=INFINITY,dk5=INFINITY,dk6=INFINITY,dk7=INFINITY;
    int   ik0=-1,ik1=-1,ik2=-1,ik3=-1,ik4=-1,ik5=-1,ik6=-1,ik7=-1;

    for (int p = 0; p < 4; ++p) {
        __syncthreads();
        const float* src = kxyz + ((size_t)(bat*NL + p*2048))*3;
        for (int i = tid; i < 6144; i += 256) sx[i] = src[i];
        const unsigned char* ps = pad + (size_t)bat*NL + p*2048;
        for (int j = tid; j < 2048; j += 256) if (ps[j]) sx[3*j] = 1e30f;
        __syncthreads();
        for (int i = 0; i < 512; ++i) {
            int jl = 4*i + tsub;
            float dx = qx - sx[3*jl+0];
            float dy = qy - sx[3*jl+1];
            float dz = qz - sx[3*jl+2];
            float cd = dx*dx + dy*dy + dz*dz;
            if (cd <= R2 && cd < dk7) {
                dk7 = cd; ik7 = p*2048 + jl;
                SWAP_STEP(dk6, dk7, ik6, ik7)
                SWAP_STEP(dk5, dk6, ik5, ik6)
                SWAP_STEP(dk4, dk5, ik4, ik5)
                SWAP_STEP(dk3, dk4, ik3, ik4)
                SWAP_STEP(dk2, dk3, ik2, ik3)
                SWAP_STEP(dk1, dk2, ik1, ik2)
                SWAP_STEP(dk0, dk1, ik0, ik1)
            }
        }
    }
    __syncthreads();
    {
        int base = tid*8;
        md[base+0]=dk0; mi[base+0]=ik0;
        md[base+1]=dk1; mi[base+1]=ik1;
        md[base+2]=dk2; mi[base+2]=ik2;
        md[base+3]=dk3; mi[base+3]=ik3;
        md[base+4]=dk4; mi[base+4]=ik4;
        md[base+5]=dk5; mi[base+5]=ik5;
        md[base+6]=dk6; mi[base+6]=ik6;
        md[base+7]=dk7; mi[base+7]=ik7;
    }
    __syncthreads();
    if (tid < 64) {
        const int mb = tid*32;
        int p0=0, p1=8, p2=16, p3=24;
        const int ob = (q0 + tid)*8;
        for (int r = 0; r < 8; ++r) {
            float h0 = (p0<8) ? md[mb+p0] : INFINITY;  int j0 = (p0<8) ? mi[mb+p0] : -1;
            float h1 = (p1<16)? md[mb+p1] : INFINITY;  int j1 = (p1<16)? mi[mb+p1] : -1;
            float h2 = (p2<24)? md[mb+p2] : INFINITY;  int j2 = (p2<24)? mi[mb+p2] : -1;
            float h3 = (p3<32)? md[mb+p3] : INFINITY;  int j3 = (p3<32)? mi[mb+p3] : -1;
            float bd = h0; int bj = j0; int bt = 0;
            if (h1 < bd || (h1 == bd && (unsigned)j1 < (unsigned)bj)) { bd=h1; bj=j1; bt=1; }
            if (h2 < bd || (h2 == bd && (unsigned)j2 < (unsigned)bj)) { bd=h2; bj=j2; bt=2; }
            if (h3 < bd || (h3 == bd && (unsigned)j3 < (unsigned)bj)) { bd=h3; bj=j3; bt=3; }
            idxout[ob + r] = (bd < 3.0e38f) ? bj : -1;
            if (bt==0) p0++; else if (bt==1) p1++; else if (bt==2) p2++; else p3++;
        }
    }
}

// ---------------------------------------------------------------------------
// Generic fp32 GEMM: out[M,N] = act(A[M,K] @ W[K,N] + bias)
// 256 threads, 32 rows x 128 cols per block, K staged in 32-chunks.
// act: 0 = none, 1 = exact gelu.
// ---------------------------------------------------------------------------
__device__ inline float gelu_exact(float x) {
    return 0.5f*x*(1.0f + erff(x*0.7071067811865476f));
}

__global__ __launch_bounds__(256) void gemm_kernel(
    const float* __restrict__ A, const float* __restrict__ W,
    const float* __restrict__ bias, float* __restrict__ out,
    int Kd, int Nd, int act)
{
    __shared__ float a_t[32*36];
    __shared__ float w_t[32*128];
    const int tid  = threadIdx.x;
    const int row0 = blockIdx.x * 32;
    const int col0 = blockIdx.y * 128;
    const int cg = tid & 31, c0 = cg*4;
    const int rg = tid >> 5, r0 = rg*4;
    const int sr = tid >> 3, scq = (tid & 7)*4;
    float acc[4][4];
    #pragma unroll
    for (int s=0;s<4;s++)
        #pragma unroll
        for (int u=0;u<4;u++) acc[s][u]=0.f;

    const int nk = Kd >> 5;
    for (int kk = 0; kk < nk; ++kk) {
        __syncthreads();
        *(float4*)&a_t[sr*36+scq] = *(const float4*)&A[(size_t)(row0+sr)*Kd + kk*32 + scq];
        #pragma unroll
        for (int t = 0; t < 4; ++t) {
            int f4i = tid + 256*t;
            int wr = f4i >> 5, wc = (f4i & 31)*4;
            *(float4*)&w_t[wr*128+wc] = *(const float4*)&W[(size_t)(kk*32+wr)*Nd + col0 + wc];
        }
        __syncthreads();
        #pragma unroll 8
        for (int i = 0; i < 32; ++i) {
            float av[4];
            #pragma unroll
            for (int s=0;s<4;s++) av[s] = a_t[(r0+s)*36 + i];
            float4 w4 = *(float4*)&w_t[i*128 + c0];
            float wv[4] = {w4.x, w4.y, w4.z, w4.w};
            #pragma unroll
            for (int s=0;s<4;s++)
                #pragma unroll
                for (int u=0;u<4;u++) acc[s][u] += av[s]*wv[u];
        }
    }
    #pragma unroll
    for (int s = 0; s < 4; ++s) {
        float o[4];
        #pragma unroll
        for (int u=0;u<4;u++) {
            float x = acc[s][u] + (bias ? bias[col0+c0+u] : 0.f);
            o[u] = (act == 1) ? gelu_exact(x) : x;
        }
        float4 ov = {o[0], o[1], o[2], o[3]};
        *(float4*)&out[(size_t)(row0+r0+s)*Nd + col0 + c0] = ov;
    }
}

// ---------------------------------------------------------------------------
// FFN2 GEMM with fused bias + residual + LayerNorm2 epilogue.
// A[M,512] @ W[512,128] + b2 + res -> LN(g,b) -> out.
// ---------------------------------------------------------------------------
__global__ __launch_bounds__(256) void gemm_ln2_kernel(
    const float* __restrict__ A, const float* __restrict__ W,
    const float* __restrict__ b2, const float* __restrict__ res,
    const float* __restrict__ g, const float* __restrict__ bb,
    float* __restrict__ out)
{
    __shared__ float a_t[32*36];
    __shared__ float w_t[32*128];
    const int tid  = threadIdx.x;
    const int row0 = blockIdx.x * 32;
    const int cg = tid & 31, c0 = cg*4;
    const int rg = tid >> 5, r0 = rg*4;
    const int sr = tid >> 3, scq = (tid & 7)*4;
    float acc[4][4];
    #pragma unroll
    for (int s=0;s<4;s++)
        #pragma unroll
        for (int u=0;u<4;u++) acc[s][u]=0.f;

    for (int kk = 0; kk < 16; ++kk) {
        __syncthreads();
        *(float4*)&a_t[sr*36+scq] = *(const float4*)&A[(size_t)(row0+sr)*NF + kk*32 + scq];
        #pragma unroll
        for (int t = 0; t < 4; ++t) {
            int f4i = tid + 256*t;
            int wr = f4i >> 5, wc = (f4i & 31)*4;
            *(float4*)&w_t[wr*128+wc] = *(const float4*)&W[(size_t)(kk*32+wr)*NC + wc];
        }
        __syncthreads();
        #pragma unroll 8
        for (int i = 0; i < 32; ++i) {
            float av[4];
            #pragma unroll
            for (int s=0;s<4;s++) av[s] = a_t[(r0+s)*36 + i];
            float4 w4 = *(float4*)&w_t[i*128 + c0];
            float wv[4] = {w4.x, w4.y, w4.z, w4.w};
            #pragma unroll
            for (int s=0;s<4;s++)
                #pragma unroll
                for (int u=0;u<4;u++) acc[s][u] += av[s]*wv[u];
        }
    }
    // epilogue: bias + residual + LN over the 128-wide row (32 lanes * 4 cols)
    float x[4][4];
    #pragma unroll
    for (int s=0;s<4;s++)
        #pragma unroll
        for (int u=0;u<4;u++)
            x[s][u] = acc[s][u] + b2[c0+u] + res[(size_t)(row0+r0+s)*NC + c0 + u];

    float sm[4];
    #pragma unroll
    for (int s=0;s<4;s++) sm[s] = x[s][0]+x[s][1]+x[s][2]+x[s][3];
    #pragma unroll
    for (int m = 1; m <= 16; m <<= 1)
        #pragma unroll
        for (int s=0;s<4;s++) sm[s] += __shfl_xor(sm[s], m);
    float mean[4];
    #pragma unroll
    for (int s=0;s<4;s++) mean[s] = sm[s]*(1.0f/128.0f);

    float vv[4];
    #pragma unroll
    for (int s=0;s<4;s++) {
        vv[s]=0.f;
        #pragma unroll
        for (int u=0;u<4;u++) { float d = x[s][u]-mean[s]; vv[s] += d*d; }
    }
    #pragma unroll
    for (int m = 1; m <= 16; m <<= 1)
        #pragma unroll
        for (int s=0;s<4;s++) vv[s] += __shfl_xor(vv[s], m);

    #pragma unroll
    for (int s=0;s<4;s++) {
        float rstd = rsqrtf(vv[s]*(1.0f/128.0f) + 1e-5f);
        float o[4];
        #pragma unroll
        for (int u=0;u<4;u++)
            o[u] = (x[s][u]-mean[s])*rstd*g[c0+u] + bb[c0+u];
        float4 ov = {o[0],o[1],o[2],o[3]};
        *(float4*)&out[(size_t)(row0+r0+s)*NC + c0] = ov;
    }
}

// ---------------------------------------------------------------------------
// Kernel: fused per-edge attention.
// 128 threads / block, 8 queries (64 edges) / block.
// h1 = relu(rel@pos_w1+b1) built in LDS; delta = relu(h1@pos_w2+b2) in regs
// (pos_w2 staged through LDS in 32-row chunks); T = adst - s_j + delta in LDS;
// alpha = relu(T@attn_w+attn_b); per-channel softmax over K=8 (reg + shfl);
// agg, residual, LN1 -> out1.
// Thread tile: 4 edges (e0..e0+3, one query) x 16 channels (c0..c0+15).
// Partner thread tid^8 holds the other 4 edges of the same query.
// ---------------------------------------------------------------------------
__global__ __launch_bounds__(128) void attn_fused_kernel(
    const float* __restrict__ qxyz, const float* __restrict__ qfeat,
    const float* __restrict__ kxyz,
    const float* __restrict__ posw1, const float* __restrict__ posb1,
    const float* __restrict__ posw2, const float* __restrict__ posb2,
    const float* __restrict__ attnw, const float* __restrict__ attnb,
    const float* __restrict__ ln1g, const float* __restrict__ ln1b,
    const int* __restrict__ idx, const float* __restrict__ vfeat,
    const float* __restrict__ sfeat, const float* __restrict__ adst,
    float* __restrict__ out1)
{
    __shared__ float ws_w[32*128];     // 16KB weight chunk
    __shared__ float ws_a[64*132];     // 33.8KB edge tile (h1, then T)
    __shared__ float s_w1[3*128];
    __shared__ float s_b1[128], s_b2[128], s_ab[128], s_g[128], s_bb[128];
    __shared__ float s_rx[64], s_ry[64], s_rz[64];
    __shared__ int   s_j[64];

    const int tid = threadIdx.x;
    const int cw = tid & 7, c0 = cw*16;
    const int ew = tid >> 3;           // 0..15
    const int e0 = ew*4;
    const int ql = ew >> 1;            // 0..7
    const int q0 = blockIdx.x * 8;
    const int bat = q0 >> 13;
    const int gq = q0 + ql;

    {   // small params: 128 threads, one element each
        int i = tid;
        s_b1[i]=posb1[i]; s_b2[i]=posb2[i]; s_ab[i]=attnb[i];
        s_g[i]=ln1g[i];   s_bb[i]=ln1b[i];
        s_w1[i]=posw1[i]; s_w1[128+i]=posw1[128+i]; s_w1[256+i]=posw1[256+i];
    }
    if (tid < 64) {
        int q = q0 + (tid >> 3);
        int j = idx[(size_t)q0*8 + tid];
        s_j[tid] = j;
        int jc = j < 0 ? 0 : j;
        const float* kp = kxyz + ((size_t)(bat*NL + jc))*3;
        s_rx[tid] = qxyz[q*3+0] - kp[0];
        s_ry[tid] = qxyz[q*3+1] - kp[1];
        s_rz[tid] = qxyz[q*3+2] - kp[2];
    }
    __syncthreads();

    // build h1 tile (this thread's 4x16 sub-block)
    {
        float rx[4], ry[4], rz[4];
        #pragma unroll
        for (int s=0;s<4;s++){ rx[s]=s_rx[e0+s]; ry[s]=s_ry[e0+s]; rz[s]=s_rz[e0+s]; }
        #pragma unroll
        for (int s=0;s<4;s++)
            #pragma unroll
            for (int c=0;c<16;c++){
                int cc = c0+c;
                float h = s_b1[cc] + rx[s]*s_w1[cc] + ry[s]*s_w1[128+cc] + rz[s]*s_w1[256+cc];
                ws_a[(e0+s)*132+cc] = fmaxf(h, 0.0f);
            }
    }

    float acc[4][16];
    #pragma unroll
    for (int s=0;s<4;s++)
        #pragma unroll
        for (int c=0;c<16;c++) acc[s][c]=0.f;

    // GEMM1: delta_pre = h1 @ pos_w2 (K staged in 4 chunks of 32 rows)
    for (int kk = 0; kk < 4; ++kk) {
        __syncthreads();
        const float* wsrc = posw2 + (size_t)kk*32*128;
        #pragma unroll
        for (int t=0;t<8;t++){
            int off = (tid + t*128)*4;
            *(float4*)&ws_w[off] = *(const float4*)&wsrc[off];
        }
        __syncthreads();
        #pragma unroll 4
        for (int i = 0; i < 32; ++i) {
            float av[4];
            #pragma unroll
            for (int s=0;s<4;s++) av[s] = ws_a[(e0+s)*132 + kk*32 + i];
            float wv[16];
            *(float4*)&wv[0]  = *(float4*)&ws_w[i*128 + c0 + 0];
            *(float4*)&wv[4]  = *(float4*)&ws_w[i*128 + c0 + 4];
            *(float4*)&wv[8]  = *(float4*)&ws_w[i*128 + c0 + 8];
            *(float4*)&wv[12] = *(float4*)&ws_w[i*128 + c0 + 12];
            #pragma unroll
            for (int s=0;s<4;s++)
                #pragma unroll
                for (int c=0;c<16;c++) acc[s][c] += av[s]*wv[c];
        }
    }

    float delta[4][16];
    #pragma unroll
    for (int s=0;s<4;s++)
        #pragma unroll
        for (int c=0;c<16;c++) delta[s][c] = fmaxf(acc[s][c] + s_b2[c0+c], 0.f);

    __syncthreads();  // everyone done reading h1 before T overwrites ws_a

    // T = adst[gq] - sfeat[j] + delta  -> ws_a
    int jr[4];
    #pragma unroll
    for (int s=0;s<4;s++){ int j = s_j[e0+s]; jr[s] = j < 0 ? 0 : j; }
    {
        float ad[16];
        const float* ap = adst + (size_t)gq*NC + c0;
        *(float4*)&ad[0]  = *(const float4*)&ap[0];
        *(float4*)&ad[4]  = *(const float4*)&ap[4];
        *(float4*)&ad[8]  = *(const float4*)&ap[8];
        *(float4*)&ad[12] = *(const float4*)&ap[12];
        #pragma unroll
        for (int s=0;s<4;s++){
            const float* sp = sfeat + ((size_t)(bat*NL + jr[s]))*NC + c0;
            #pragma unroll
            for (int u=0;u<4;u++){
                float4 sv = *(const float4*)&sp[4*u];
                float4 tv;
                tv.x = ad[4*u+0] - sv.x + delta[s][4*u+0];
                tv.y = ad[4*u+1] - sv.y + delta[s][4*u+1];
                tv.z = ad[4*u+2] - sv.z + delta[s][4*u+2];
                tv.w = ad[4*u+3] - sv.w + delta[s][4*u+3];
                *(float4*)&ws_a[(e0+s)*132 + c0 + 4*u] = tv;
            }
        }
    }

    #pragma unroll
    for (int s=0;s<4;s++)
        #pragma unroll
        for (int c=0;c<16;c++) acc[s][c]=0.f;

    // GEMM2: alpha_pre = T @ attn_w
    for (int kk = 0; kk < 4; ++kk) {
        __syncthreads();
        const float* wsrc = attnw + (size_t)kk*32*128;
        #pragma unroll
        for (int t=0;t<8;t++){
            int off = (tid + t*128)*4;
            *(float4*)&ws_w[off] = *(const float4*)&wsrc[off];
        }
        __syncthreads();
        #pragma unroll 4
        for (int i = 0; i < 32; ++i) {
            float av[4];
            #pragma unroll
            for (int s=0;s<4;s++) av[s] = ws_a[(e0+s)*132 + kk*32 + i];
            float wv[16];
            *(float4*)&wv[0]  = *(float4*)&ws_w[i*128 + c0 + 0];
            *(float4*)&wv[4]  = *(float4*)&ws_w[i*128 + c0 + 4];
            *(float4*)&wv[8]  = *(float4*)&ws_w[i*128 + c0 + 8];
            *(float4*)&wv[12] = *(float4*)&ws_w[i*128 + c0 + 12];
            #pragma unroll
            for (int s=0;s<4;s++)
                #pragma unroll
                for (int c=0;c<16;c++) acc[s][c] += av[s]*wv[c];
        }
    }

    // alpha -> masked scores -> per-channel softmax over the 8 edges
    bool val[4];
    #pragma unroll
    for (int s=0;s<4;s++) val[s] = (s_j[e0+s] >= 0);
    float sc[4][16];
    #pragma unroll
    for (int s=0;s<4;s++)
        #pragma unroll
        for (int c=0;c<16;c++){
            float a = fmaxf(acc[s][c] + s_ab[c0+c], 0.f);
            sc[s][c] = val[s] ? a : -INFINITY;
        }

    float mx[16], dnm[16];
    #pragma unroll
    for (int c=0;c<16;c++){
        float m = fmaxf(fmaxf(sc[0][c], sc[1][c]), fmaxf(sc[2][c], sc[3][c]));
        m = fmaxf(m, __shfl_xor(m, 8));
        if (m == -INFINITY) m = 0.f;
        mx[c] = m;
    }
    #pragma unroll
    for (int s=0;s<4;s++)
        #pragma unroll
        for (int c=0;c<16;c++)
            sc[s][c] = val[s] ? expf(sc[s][c] - mx[c]) : 0.f;
    #pragma unroll
    for (int c=0;c<16;c++){
        float sum = sc[0][c]+sc[1][c]+sc[2][c]+sc[3][c];
        sum += __shfl_xor(sum, 8);
        dnm[c] = fmaxf(sum, 1e-12f);
    }

    // agg = sum_k attn * (x_j + delta)
    float part[16];
    #pragma unroll
    for (int c=0;c<16;c++) part[c]=0.f;
    #pragma unroll
    for (int s=0;s<4;s++){
        const float* vp = vfeat + ((size_t)(bat*NL + jr[s]))*NC + c0;
        #pragma unroll
        for (int u=0;u<4;u++){
            float4 xv = *(const float4*)&vp[4*u];
            part[4*u+0] += sc[s][4*u+0]*(xv.x + delta[s][4*u+0]);
            part[4*u+1] += sc[s][4*u+1]*(xv.y + delta[s][4*u+1]);
            part[4*u+2] += sc[s][4*u+2]*(xv.z + delta[s][4*u+2]);
            part[4*u+3] += sc[s][4*u+3]*(xv.w + delta[s][4*u+3]);
        }
    }
    float xln[16];
    {
        const float* qp = qfeat + (size_t)gq*NC + c0;
        #pragma unroll
        for (int c=0;c<16;c++){
            float agg = part[c]/dnm[c];
            agg += __shfl_xor(agg, 8);
            xln[c] = qp[c] + agg;
        }
    }
    // LN1 over 16-lane group (8 cw * 2 ew-parities; channels counted twice -> /256)
    float sm = 0.f;
    #pragma unroll
    for (int c=0;c<16;c++) sm += xln[c];
    #pragma unroll
    for (int m = 1; m <= 8; m <<= 1) sm += __shfl_xor(sm, m);
    float mean = sm*(1.0f/256.0f);
    float vv = 0.f;
    #pragma unroll
    for (int c=0;c<16;c++){ float d = xln[c]-mean; vv += d*d; }
    #pragma unroll
    for (int m = 1; m <= 8; m <<= 1) vv += __shfl_xor(vv, m);
    float rstd = rsqrtf(vv*(1.0f/256.0f) + 1e-5f);

    if ((ew & 1) == 0) {
        float* op = out1 + (size_t)gq*NC + c0;
        #pragma unroll
        for (int u=0;u<4;u++){
            float4 ov;
            ov.x = (xln[4*u+0]-mean)*rstd*s_g[c0+4*u+0] + s_bb[c0+4*u+0];
            ov.y = (xln[4*u+1]-mean)*rstd*s_g[c0+4*u+1] + s_bb[c0+4*u+1];
            ov.z = (xln[4*u+2]-mean)*rstd*s_g[c0+4*u+2] + s_bb[c0+4*u+2];
            ov.w = (xln[4*u+3]-mean)*rstd*s_g[c0+4*u+3] + s_bb[c0+4*u+3];
            *(float4*)&op[4*u] = ov;
        }
    }
}

// ---------------------------------------------------------------------------
extern "C" void kernel_launch(void* const* d_in, const int* in_sizes, int n_in,
                              void* d_out, int out_size, void* d_ws, size_t ws_size,
                              hipStream_t stream)
{
    (void)in_sizes; (void)n_in; (void)out_size; (void)ws_size;
    const float* q_xyz   = (const float*)d_in[0];
    const float* q_feat  = (const float*)d_in[1];
    const float* kv_xyz  = (const float*)d_in[2];
    const float* kv_feat = (const float*)d_in[3];
    const unsigned char* kv_pad = (const unsigned char*)d_in[4];
    const float* pos_w1  = (const float*)d_in[5];
    const float* pos_b1  = (const float*)d_in[6];
    const float* pos_w2  = (const float*)d_in[7];
    const float* pos_b2  = (const float*)d_in[8];
    const float* attn_w  = (const float*)d_in[9];
    const float* attn_b  = (const float*)d_in[10];
    const float* lin_w   = (const float*)d_in[11];
    const float* lin_src_w = (const float*)d_in[12];
    const float* lin_dst_w = (const float*)d_in[13];
    const float* ln1_g   = (const float*)d_in[14];
    const float* ln1_b   = (const float*)d_in[15];
    const float* ffn_w1  = (const float*)d_in[16];
    const float* ffn_b1  = (const float*)d_in[17];
    const float* ffn_w2  = (const float*)d_in[18];
    const float* ffn_b2  = (const float*)d_in[19];
    const float* ln2_g   = (const float*)d_in[20];
    const float* ln2_b   = (const float*)d_in[21];

    float* ws    = (float*)d_ws;
    int*   idx   = (int*)d_ws;                       // MQ*8 ints
    float* vfeat = ws + 131072;                      // [MQ, 128]
    float* sfeat = vfeat + (size_t)MQ*NC;            // [MQ, 128]
    float* adst  = sfeat + (size_t)MQ*NC;            // [MQ, 128]
    float* out1  = adst  + (size_t)MQ*NC;            // [MQ, 128]
    float* Hbuf  = out1  + (size_t)MQ*NC;            // [MQ, 512]

    radius_topk_kernel<<<dim3(MQ/64), dim3(256), 0, stream>>>(q_xyz, kv_xyz, kv_pad, idx);

    gemm_kernel<<<dim3(MQ/32, 1), dim3(256), 0, stream>>>(kv_feat, lin_w,     nullptr, vfeat, 128, 128, 0);
    gemm_kernel<<<dim3(MQ/32, 1), dim3(256), 0, stream>>>(kv_feat, lin_src_w, nullptr, sfeat, 128, 128, 0);
    gemm_kernel<<<dim3(MQ/32, 1), dim3(256), 0, stream>>>(q_feat,  lin_dst_w, nullptr, adst,  128, 128, 0);

    attn_fused_kernel<<<dim3(MQ/8), dim3(128), 0, stream>>>(
        q_xyz, q_feat, kv_xyz,
        pos_w1, pos_b1, pos_w2, pos_b2, attn_w, attn_b,
        ln1_g, ln1_b, idx, vfeat, sfeat, adst, out1);

    gemm_kernel<<<dim3(MQ/32, 4), dim3(256), 0, stream>>>(out1, ffn_w1, ffn_b1, Hbuf, 128, 512, 1);
    gemm_ln2_kernel<<<dim3(MQ/32, 1), dim3(256), 0, stream>>>(Hbuf, ffn_w2, ffn_b2, out1, ln2_g, ln2_b, (float*)d_out);
}

// Round 3
// 581.094 us; speedup vs baseline: 1.3087x; 1.3087x over previous
//
#include <hip/hip_runtime.h>
#include <math.h>

#define NB 2
#define NQ 8192
#define NL 8192
#define NC 128
#define NKN 8
#define NF 512
#define MQ (NB*NQ)   // 16384 rows total (both batches)

// ---------------------------------------------------------------------------
// Kernel 1: radius graph + top-8 nearest within RADIUS.
// 256 threads / block, 16 queries / block (1024 blocks), 16 threads / query.
// kv_xyz staged SoA in LDS in 4 passes of 2048 points; each thread scans a
// CONTIGUOUS 128-point segment (padded stride 132 -> ds_read_b128, 2-way
// bank aliasing only). Per-thread sorted top-8 in registers; the 16 partial
// lists of a query merge via __shfl_xor bitonic min-half rounds (no LDS).
// Neighbor ORDER doesn't affect the final output (softmax over K is
// set-invariant), so any consistent merge is fine.
// ---------------------------------------------------------------------------
__global__ __launch_bounds__(256) void radius_topk_kernel(
    const float* __restrict__ qxyz, const float* __restrict__ kxyz,
    const unsigned char* __restrict__ pad, int* __restrict__ idxout)
{
    __shared__ float sxx[16*132], sxy[16*132], sxz[16*132];
    const int tid = threadIdx.x;
    const int ts  = tid & 15;          // sub-lane within query group
    const int ql  = tid >> 4;          // local query 0..15
    const int q0  = blockIdx.x * 16;
    const int gq  = q0 + ql;
    const int bat = gq >> 13;
    const float qx = qxyz[gq*3+0], qy = qxyz[gq*3+1], qz = qxyz[gq*3+2];
    const float R2  = (float)(0.4*0.4);
    // sentinel: one ulp above R2 (nextafterf is a libcall on device -> do it in bits)
    const float R2P = __uint_as_float(__float_as_uint(R2) + 1u);

    float dk[8]; int ik[8];
    #pragma unroll
    for (int r = 0; r < 8; ++r) { dk[r] = R2P; ik[r] = -1; }

    const float* kbase = kxyz + (size_t)bat*NL*3;
    const unsigned char* pbase = pad + (size_t)bat*NL;

    for (int p = 0; p < 4; ++p) {
        __syncthreads();
        const float* src = kbase + (size_t)p*2048*3;
        #pragma unroll
        for (int k = 0; k < 8; ++k) {
            int j = tid + k*256;
            int a = ((j >> 7)*132) + (j & 127);
            sxx[a] = src[3*j+0];
            sxy[a] = src[3*j+1];
            sxz[a] = src[3*j+2];
        }
        const unsigned char* ps = pbase + p*2048;
        #pragma unroll
        for (int k = 0; k < 8; ++k) {
            int j = tid + k*256;
            if (ps[j]) sxx[((j >> 7)*132) + (j & 127)] = 1e30f;
        }
        __syncthreads();

        const float* px = sxx + ts*132;
        const float* py = sxy + ts*132;
        const float* pz = sxz + ts*132;
        const int ibase = p*2048 + ts*128;

        for (int i = 0; i < 128; i += 4) {
            float4 vx = *(const float4*)&px[i];
            float4 vy = *(const float4*)&py[i];
            float4 vz = *(const float4*)&pz[i];
            float dx, dy, dz;
            dx = qx-vx.x; dy = qy-vy.x; dz = qz-vz.x;
            float c0 = dx*dx + dy*dy + dz*dz;
            dx = qx-vx.y; dy = qy-vy.y; dz = qz-vz.y;
            float c1 = dx*dx + dy*dy + dz*dz;
            dx = qx-vx.z; dy = qy-vy.z; dz = qz-vz.z;
            float c2 = dx*dx + dy*dy + dz*dz;
            dx = qx-vx.w; dy = qy-vy.w; dz = qz-vz.w;
            float c3 = dx*dx + dy*dy + dz*dz;
            float m = fminf(fminf(c0, c1), fminf(c2, c3));
            if (m < dk[7]) {
                float cc[4] = {c0, c1, c2, c3};
                #pragma unroll
                for (int u = 0; u < 4; ++u) {
                    if (cc[u] < dk[7]) {
                        dk[7] = cc[u]; ik[7] = ibase + i + u;
                        #pragma unroll
                        for (int r = 6; r >= 0; --r) {
                            bool sw = dk[r+1] < dk[r];
                            float td = dk[r]; int ti = ik[r];
                            dk[r]   = sw ? dk[r+1] : dk[r];
                            ik[r]   = sw ? ik[r+1] : ik[r];
                            dk[r+1] = sw ? td : dk[r+1];
                            ik[r+1] = sw ? ti : ik[r+1];
                        }
                    }
                }
            }
        }
    }

    // merge the 16 per-lane sorted lists of this query group (shuffle bitonic)
    #pragma unroll
    for (int m = 1; m <= 8; m <<= 1) {
        float od[8]; int oi[8];
        #pragma unroll
        for (int r = 0; r < 8; ++r) {
            od[r] = __shfl_xor(dk[r], m);
            oi[r] = __shfl_xor(ik[r], m);
        }
        // keep the 8 smallest of the 16: nd[r] = min(dk[r], od[7-r]) (bitonic)
        float nd[8]; int ni[8];
        #pragma unroll
        for (int r = 0; r < 8; ++r) {
            bool take = od[7-r] < dk[r];
            nd[r] = take ? od[7-r] : dk[r];
            ni[r] = take ? oi[7-r] : ik[r];
        }
        // bitonic sort-8 of nd: stages 4, 2, 1
        #pragma unroll
        for (int st = 4; st >= 1; st >>= 1) {
            #pragma unroll
            for (int r = 0; r < 8; ++r) {
                if ((r & st) == 0 && (r | st) < 8) {
                    int b = r | st;
                    bool sw = nd[b] < nd[r];
                    float td = nd[r]; int ti = ni[r];
                    nd[r] = sw ? nd[b] : nd[r];
                    ni[r] = sw ? ni[b] : ni[r];
                    nd[b] = sw ? td : nd[b];
                    ni[b] = sw ? ti : ni[b];
                }
            }
        }
        #pragma unroll
        for (int r = 0; r < 8; ++r) { dk[r] = nd[r]; ik[r] = ni[r]; }
    }

    if (ts == 0) {
        int o[8];
        #pragma unroll
        for (int r = 0; r < 8; ++r) o[r] = (dk[r] <= R2) ? ik[r] : -1;
        int4 a = {o[0], o[1], o[2], o[3]};
        int4 b = {o[4], o[5], o[6], o[7]};
        *(int4*)&idxout[(size_t)gq*8 + 0] = a;
        *(int4*)&idxout[(size_t)gq*8 + 4] = b;
    }
}

// ---------------------------------------------------------------------------
// Generic fp32 GEMM: out[M,N] = act(A[M,K] @ W[K,N] + bias)
// 256 threads, 32 rows x 128 cols per block, K staged in 32-chunks.
// act: 0 = none, 1 = exact gelu.
// ---------------------------------------------------------------------------
__device__ inline float gelu_exact(float x) {
    return 0.5f*x*(1.0f + erff(x*0.7071067811865476f));
}

__global__ __launch_bounds__(256) void gemm_kernel(
    const float* __restrict__ A, const float* __restrict__ W,
    const float* __restrict__ bias, float* __restrict__ out,
    int Kd, int Nd, int act)
{
    __shared__ float a_t[32*36];
    __shared__ float w_t[32*128];
    const int tid  = threadIdx.x;
    const int row0 = blockIdx.x * 32;
    const int col0 = blockIdx.y * 128;
    const int cg = tid & 31, c0 = cg*4;
    const int rg = tid >> 5, r0 = rg*4;
    const int sr = tid >> 3, scq = (tid & 7)*4;
    float acc[4][4];
    #pragma unroll
    for (int s=0;s<4;s++)
        #pragma unroll
        for (int u=0;u<4;u++) acc[s][u]=0.f;

    const int nk = Kd >> 5;
    for (int kk = 0; kk < nk; ++kk) {
        __syncthreads();
        *(float4*)&a_t[sr*36+scq] = *(const float4*)&A[(size_t)(row0+sr)*Kd + kk*32 + scq];
        #pragma unroll
        for (int t = 0; t < 4; ++t) {
            int f4i = tid + 256*t;
            int wr = f4i >> 5, wc = (f4i & 31)*4;
            *(float4*)&w_t[wr*128+wc] = *(const float4*)&W[(size_t)(kk*32+wr)*Nd + col0 + wc];
        }
        __syncthreads();
        #pragma unroll 8
        for (int i = 0; i < 32; ++i) {
            float av[4];
            #pragma unroll
            for (int s=0;s<4;s++) av[s] = a_t[(r0+s)*36 + i];
            float4 w4 = *(float4*)&w_t[i*128 + c0];
            float wv[4] = {w4.x, w4.y, w4.z, w4.w};
            #pragma unroll
            for (int s=0;s<4;s++)
                #pragma unroll
                for (int u=0;u<4;u++) acc[s][u] += av[s]*wv[u];
        }
    }
    #pragma unroll
    for (int s = 0; s < 4; ++s) {
        float o[4];
        #pragma unroll
        for (int u=0;u<4;u++) {
            float x = acc[s][u] + (bias ? bias[col0+c0+u] : 0.f);
            o[u] = (act == 1) ? gelu_exact(x) : x;
        }
        float4 ov = {o[0], o[1], o[2], o[3]};
        *(float4*)&out[(size_t)(row0+r0+s)*Nd + col0 + c0] = ov;
    }
}

// ---------------------------------------------------------------------------
// FFN2 GEMM with fused bias + residual + LayerNorm2 epilogue.
// A[M,512] @ W[512,128] + b2 + res -> LN(g,b) -> out.
// ---------------------------------------------------------------------------
__global__ __launch_bounds__(256) void gemm_ln2_kernel(
    const float* __restrict__ A, const float* __restrict__ W,
    const float* __restrict__ b2, const float* __restrict__ res,
    const float* __restrict__ g, const float* __restrict__ bb,
    float* __restrict__ out)
{
    __shared__ float a_t[32*36];
    __shared__ float w_t[32*128];
    const int tid  = threadIdx.x;
    const int row0 = blockIdx.x * 32;
    const int cg = tid & 31, c0 = cg*4;
    const int rg = tid >> 5, r0 = rg*4;
    const int sr = tid >> 3, scq = (tid & 7)*4;
    float acc[4][4];
    #pragma unroll
    for (int s=0;s<4;s++)
        #pragma unroll
        for (int u=0;u<4;u++) acc[s][u]=0.f;

    for (int kk = 0; kk < 16; ++kk) {
        __syncthreads();
        *(float4*)&a_t[sr*36+scq] = *(const float4*)&A[(size_t)(row0+sr)*NF + kk*32 + scq];
        #pragma unroll
        for (int t = 0; t < 4; ++t) {
            int f4i = tid + 256*t;
            int wr = f4i >> 5, wc = (f4i & 31)*4;
            *(float4*)&w_t[wr*128+wc] = *(const float4*)&W[(size_t)(kk*32+wr)*NC + wc];
        }
        __syncthreads();
        #pragma unroll 8
        for (int i = 0; i < 32; ++i) {
            float av[4];
            #pragma unroll
            for (int s=0;s<4;s++) av[s] = a_t[(r0+s)*36 + i];
            float4 w4 = *(float4*)&w_t[i*128 + c0];
            float wv[4] = {w4.x, w4.y, w4.z, w4.w};
            #pragma unroll
            for (int s=0;s<4;s++)
                #pragma unroll
                for (int u=0;u<4;u++) acc[s][u] += av[s]*wv[u];
        }
    }
    // epilogue: bias + residual + LN over the 128-wide row (32 lanes * 4 cols)
    float x[4][4];
    #pragma unroll
    for (int s=0;s<4;s++)
        #pragma unroll
        for (int u=0;u<4;u++)
            x[s][u] = acc[s][u] + b2[c0+u] + res[(size_t)(row0+r0+s)*NC + c0 + u];

    float sm[4];
    #pragma unroll
    for (int s=0;s<4;s++) sm[s] = x[s][0]+x[s][1]+x[s][2]+x[s][3];
    #pragma unroll
    for (int m = 1; m <= 16; m <<= 1)
        #pragma unroll
        for (int s=0;s<4;s++) sm[s] += __shfl_xor(sm[s], m);
    float mean[4];
    #pragma unroll
    for (int s=0;s<4;s++) mean[s] = sm[s]*(1.0f/128.0f);

    float vv[4];
    #pragma unroll
    for (int s=0;s<4;s++) {
        vv[s]=0.f;
        #pragma unroll
        for (int u=0;u<4;u++) { float d = x[s][u]-mean[s]; vv[s] += d*d; }
    }
    #pragma unroll
    for (int m = 1; m <= 16; m <<= 1)
        #pragma unroll
        for (int s=0;s<4;s++) vv[s] += __shfl_xor(vv[s], m);

    #pragma unroll
    for (int s=0;s<4;s++) {
        float rstd = rsqrtf(vv[s]*(1.0f/128.0f) + 1e-5f);
        float o[4];
        #pragma unroll
        for (int u=0;u<4;u++)
            o[u] = (x[s][u]-mean[s])*rstd*g[c0+u] + bb[c0+u];
        float4 ov = {o[0],o[1],o[2],o[3]};
        *(float4*)&out[(size_t)(row0+r0+s)*NC + c0] = ov;
    }
}

// ---------------------------------------------------------------------------
// Kernel: fused per-edge attention.
// 128 threads / block, 8 queries (64 edges) / block.
// h1 = relu(rel@pos_w1+b1) built in LDS; delta = relu(h1@pos_w2+b2) in regs
// (pos_w2 staged through LDS in 32-row chunks); T = adst - s_j + delta in LDS;
// alpha = relu(T@attn_w+attn_b); per-channel softmax over K=8 (reg + shfl);
// agg, residual, LN1 -> out1.
// Thread tile: 4 edges (e0..e0+3, one query) x 16 channels (c0..c0+15).
// Partner thread tid^8 holds the other 4 edges of the same query.
// ---------------------------------------------------------------------------
__global__ __launch_bounds__(128) void attn_fused_kernel(
    const float* __restrict__ qxyz, const float* __restrict__ qfeat,
    const float* __restrict__ kxyz,
    const float* __restrict__ posw1, const float* __restrict__ posb1,
    const float* __restrict__ posw2, const float* __restrict__ posb2,
    const float* __restrict__ attnw, const float* __restrict__ attnb,
    const float* __restrict__ ln1g, const float* __restrict__ ln1b,
    const int* __restrict__ idx, const float* __restrict__ vfeat,
    const float* __restrict__ sfeat, const float* __restrict__ adst,
    float* __restrict__ out1)
{
    __shared__ float ws_w[32*128];     // 16KB weight chunk
    __shared__ float ws_a[64*132];     // 33.8KB edge tile (h1, then T)
    __shared__ float s_w1[3*128];
    __shared__ float s_b1[128], s_b2[128], s_ab[128], s_g[128], s_bb[128];
    __shared__ float s_rx[64], s_ry[64], s_rz[64];
    __shared__ int   s_j[64];

    const int tid = threadIdx.x;
    const int cw = tid & 7, c0 = cw*16;
    const int ew = tid >> 3;           // 0..15
    const int e0 = ew*4;
    const int ql = ew >> 1;            // 0..7
    const int q0 = blockIdx.x * 8;
    const int bat = q0 >> 13;
    const int gq = q0 + ql;

    {   // small params: 128 threads, one element each
        int i = tid;
        s_b1[i]=posb1[i]; s_b2[i]=posb2[i]; s_ab[i]=attnb[i];
        s_g[i]=ln1g[i];   s_bb[i]=ln1b[i];
        s_w1[i]=posw1[i]; s_w1[128+i]=posw1[128+i]; s_w1[256+i]=posw1[256+i];
    }
    if (tid < 64) {
        int q = q0 + (tid >> 3);
        int j = idx[(size_t)q0*8 + tid];
        s_j[tid] = j;
        int jc = j < 0 ? 0 : j;
        const float* kp = kxyz + ((size_t)(bat*NL + jc))*3;
        s_rx[tid] = qxyz[q*3+0] - kp[0];
        s_ry[tid] = qxyz[q*3+1] - kp[1];
        s_rz[tid] = qxyz[q*3+2] - kp[2];
    }
    __syncthreads();

    // build h1 tile (this thread's 4x16 sub-block)
    {
        float rx[4], ry[4], rz[4];
        #pragma unroll
        for (int s=0;s<4;s++){ rx[s]=s_rx[e0+s]; ry[s]=s_ry[e0+s]; rz[s]=s_rz[e0+s]; }
        #pragma unroll
        for (int s=0;s<4;s++)
            #pragma unroll
            for (int c=0;c<16;c++){
                int cc = c0+c;
                float h = s_b1[cc] + rx[s]*s_w1[cc] + ry[s]*s_w1[128+cc] + rz[s]*s_w1[256+cc];
                ws_a[(e0+s)*132+cc] = fmaxf(h, 0.0f);
            }
    }

    float acc[4][16];
    #pragma unroll
    for (int s=0;s<4;s++)
        #pragma unroll
        for (int c=0;c<16;c++) acc[s][c]=0.f;

    // GEMM1: delta_pre = h1 @ pos_w2 (K staged in 4 chunks of 32 rows)
    for (int kk = 0; kk < 4; ++kk) {
        __syncthreads();
        const float* wsrc = posw2 + (size_t)kk*32*128;
        #pragma unroll
        for (int t=0;t<8;t++){
            int off = (tid + t*128)*4;
            *(float4*)&ws_w[off] = *(const float4*)&wsrc[off];
        }
        __syncthreads();
        #pragma unroll 4
        for (int i = 0; i < 32; ++i) {
            float av[4];
            #pragma unroll
            for (int s=0;s<4;s++) av[s] = ws_a[(e0+s)*132 + kk*32 + i];
            float wv[16];
            *(float4*)&wv[0]  = *(float4*)&ws_w[i*128 + c0 + 0];
            *(float4*)&wv[4]  = *(float4*)&ws_w[i*128 + c0 + 4];
            *(float4*)&wv[8]  = *(float4*)&ws_w[i*128 + c0 + 8];
            *(float4*)&wv[12] = *(float4*)&ws_w[i*128 + c0 + 12];
            #pragma unroll
            for (int s=0;s<4;s++)
                #pragma unroll
                for (int c=0;c<16;c++) acc[s][c] += av[s]*wv[c];
        }
    }

    float delta[4][16];
    #pragma unroll
    for (int s=0;s<4;s++)
        #pragma unroll
        for (int c=0;c<16;c++) delta[s][c] = fmaxf(acc[s][c] + s_b2[c0+c], 0.f);

    __syncthreads();  // everyone done reading h1 before T overwrites ws_a

    // T = adst[gq] - sfeat[j] + delta  -> ws_a
    int jr[4];
    #pragma unroll
    for (int s=0;s<4;s++){ int j = s_j[e0+s]; jr[s] = j < 0 ? 0 : j; }
    {
        float ad[16];
        const float* ap = adst + (size_t)gq*NC + c0;
        *(float4*)&ad[0]  = *(const float4*)&ap[0];
        *(float4*)&ad[4]  = *(const float4*)&ap[4];
        *(float4*)&ad[8]  = *(const float4*)&ap[8];
        *(float4*)&ad[12] = *(const float4*)&ap[12];
        #pragma unroll
        for (int s=0;s<4;s++){
            const float* sp = sfeat + ((size_t)(bat*NL + jr[s]))*NC + c0;
            #pragma unroll
            for (int u=0;u<4;u++){
                float4 sv = *(const float4*)&sp[4*u];
                float4 tv;
                tv.x = ad[4*u+0] - sv.x + delta[s][4*u+0];
                tv.y = ad[4*u+1] - sv.y + delta[s][4*u+1];
                tv.z = ad[4*u+2] - sv.z + delta[s][4*u+2];
                tv.w = ad[4*u+3] - sv.w + delta[s][4*u+3];
                *(float4*)&ws_a[(e0+s)*132 + c0 + 4*u] = tv;
            }
        }
    }

    #pragma unroll
    for (int s=0;s<4;s++)
        #pragma unroll
        for (int c=0;c<16;c++) acc[s][c]=0.f;

    // GEMM2: alpha_pre = T @ attn_w
    for (int kk = 0; kk < 4; ++kk) {
        __syncthreads();
        const float* wsrc = attnw + (size_t)kk*32*128;
        #pragma unroll
        for (int t=0;t<8;t++){
            int off = (tid + t*128)*4;
            *(float4*)&ws_w[off] = *(const float4*)&wsrc[off];
        }
        __syncthreads();
        #pragma unroll 4
        for (int i = 0; i < 32; ++i) {
            float av[4];
            #pragma unroll
            for (int s=0;s<4;s++) av[s] = ws_a[(e0+s)*132 + kk*32 + i];
            float wv[16];
            *(float4*)&wv[0]  = *(float4*)&ws_w[i*128 + c0 + 0];
            *(float4*)&wv[4]  = *(float4*)&ws_w[i*128 + c0 + 4];
            *(float4*)&wv[8]  = *(float4*)&ws_w[i*128 + c0 + 8];
            *(float4*)&wv[12] = *(float4*)&ws_w[i*128 + c0 + 12];
            #pragma unroll
            for (int s=0;s<4;s++)
                #pragma unroll
                for (int c=0;c<16;c++) acc[s][c] += av[s]*wv[c];
        }
    }

    // alpha -> masked scores -> per-channel softmax over the 8 edges
    bool val[4];
    #pragma unroll
    for (int s=0;s<4;s++) val[s] = (s_j[e0+s] >= 0);
    float sc[4][16];
    #pragma unroll
    for (int s=0;s<4;s++)
        #pragma unroll
        for (int c=0;c<16;c++){
            float a = fmaxf(acc[s][c] + s_ab[c0+c], 0.f);
            sc[s][c] = val[s] ? a : -INFINITY;
        }

    float mx[16], dnm[16];
    #pragma unroll
    for (int c=0;c<16;c++){
        float m = fmaxf(fmaxf(sc[0][c], sc[1][c]), fmaxf(sc[2][c], sc[3][c]));
        m = fmaxf(m, __shfl_xor(m, 8));
        if (m == -INFINITY) m = 0.f;
        mx[c] = m;
    }
    #pragma unroll
    for (int s=0;s<4;s++)
        #pragma unroll
        for (int c=0;c<16;c++)
            sc[s][c] = val[s] ? expf(sc[s][c] - mx[c]) : 0.f;
    #pragma unroll
    for (int c=0;c<16;c++){
        float sum = sc[0][c]+sc[1][c]+sc[2][c]+sc[3][c];
        sum += __shfl_xor(sum, 8);
        dnm[c] = fmaxf(sum, 1e-12f);
    }

    // agg = sum_k attn * (x_j + delta)
    float part[16];
    #pragma unroll
    for (int c=0;c<16;c++) part[c]=0.f;
    #pragma unroll
    for (int s=0;s<4;s++){
        const float* vp = vfeat + ((size_t)(bat*NL + jr[s]))*NC + c0;
        #pragma unroll
        for (int u=0;u<4;u++){
            float4 xv = *(const float4*)&vp[4*u];
            part[4*u+0] += sc[s][4*u+0]*(xv.x + delta[s][4*u+0]);
            part[4*u+1] += sc[s][4*u+1]*(xv.y + delta[s][4*u+1]);
            part[4*u+2] += sc[s][4*u+2]*(xv.z + delta[s][4*u+2]);
            part[4*u+3] += sc[s][4*u+3]*(xv.w + delta[s][4*u+3]);
        }
    }
    float xln[16];
    {
        const float* qp = qfeat + (size_t)gq*NC + c0;
        #pragma unroll
        for (int c=0;c<16;c++){
            float agg = part[c]/dnm[c];
            agg += __shfl_xor(agg, 8);
            xln[c] = qp[c] + agg;
        }
    }
    // LN1 over 16-lane group (8 cw * 2 ew-parities; channels counted twice -> /256)
    float sm = 0.f;
    #pragma unroll
    for (int c=0;c<16;c++) sm += xln[c];
    #pragma unroll
    for (int m = 1; m <= 8; m <<= 1) sm += __shfl_xor(sm, m);
    float mean = sm*(1.0f/256.0f);
    float vv = 0.f;
    #pragma unroll
    for (int c=0;c<16;c++){ float d = xln[c]-mean; vv += d*d; }
    #pragma unroll
    for (int m = 1; m <= 8; m <<= 1) vv += __shfl_xor(vv, m);
    float rstd = rsqrtf(vv*(1.0f/256.0f) + 1e-5f);

    if ((ew & 1) == 0) {
        float* op = out1 + (size_t)gq*NC + c0;
        #pragma unroll
        for (int u=0;u<4;u++){
            float4 ov;
            ov.x = (xln[4*u+0]-mean)*rstd*s_g[c0+4*u+0] + s_bb[c0+4*u+0];
            ov.y = (xln[4*u+1]-mean)*rstd*s_g[c0+4*u+1] + s_bb[c0+4*u+1];
            ov.z = (xln[4*u+2]-mean)*rstd*s_g[c0+4*u+2] + s_bb[c0+4*u+2];
            ov.w = (xln[4*u+3]-mean)*rstd*s_g[c0+4*u+3] + s_bb[c0+4*u+3];
            *(float4*)&op[4*u] = ov;
        }
    }
}

// ---------------------------------------------------------------------------
extern "C" void kernel_launch(void* const* d_in, const int* in_sizes, int n_in,
                              void* d_out, int out_size, void* d_ws, size_t ws_size,
                              hipStream_t stream)
{
    (void)in_sizes; (void)n_in; (void)out_size; (void)ws_size;
    const float* q_xyz   = (const float*)d_in[0];
    const float* q_feat  = (const float*)d_in[1];
    const float* kv_xyz  = (const float*)d_in[2];
    const float* kv_feat = (const float*)d_in[3];
    const unsigned char* kv_pad = (const unsigned char*)d_in[4];
    const float* pos_w1  = (const float*)d_in[5];
    const float* pos_b1  = (const float*)d_in[6];
    const float* pos_w2  = (const float*)d_in[7];
    const float* pos_b2  = (const float*)d_in[8];
    const float* attn_w  = (const float*)d_in[9];
    const float* attn_b  = (const float*)d_in[10];
    const float* lin_w   = (const float*)d_in[11];
    const float* lin_src_w = (const float*)d_in[12];
    const float* lin_dst_w = (const float*)d_in[13];
    const float* ln1_g   = (const float*)d_in[14];
    const float* ln1_b   = (const float*)d_in[15];
    const float* ffn_w1  = (const float*)d_in[16];
    const float* ffn_b1  = (const float*)d_in[17];
    const float* ffn_w2  = (const float*)d_in[18];
    const float* ffn_b2  = (const float*)d_in[19];
    const float* ln2_g   = (const float*)d_in[20];
    const float* ln2_b   = (const float*)d_in[21];

    float* ws    = (float*)d_ws;
    int*   idx   = (int*)d_ws;                       // MQ*8 ints
    float* vfeat = ws + 131072;                      // [MQ, 128]
    float* sfeat = vfeat + (size_t)MQ*NC;            // [MQ, 128]
    float* adst  = sfeat + (size_t)MQ*NC;            // [MQ, 128]
    float* out1  = adst  + (size_t)MQ*NC;            // [MQ, 128]
    float* Hbuf  = out1  + (size_t)MQ*NC;            // [MQ, 512]

    radius_topk_kernel<<<dim3(MQ/16), dim3(256), 0, stream>>>(q_xyz, kv_xyz, kv_pad, idx);

    gemm_kernel<<<dim3(MQ/32, 1), dim3(256), 0, stream>>>(kv_feat, lin_w,     nullptr, vfeat, 128, 128, 0);
    gemm_kernel<<<dim3(MQ/32, 1), dim3(256), 0, stream>>>(kv_feat, lin_src_w, nullptr, sfeat, 128, 128, 0);
    gemm_kernel<<<dim3(MQ/32, 1), dim3(256), 0, stream>>>(q_feat,  lin_dst_w, nullptr, adst,  128, 128, 0);

    attn_fused_kernel<<<dim3(MQ/8), dim3(128), 0, stream>>>(
        q_xyz, q_feat, kv_xyz,
        pos_w1, pos_b1, pos_w2, pos_b2, attn_w, attn_b,
        ln1_g, ln1_b, idx, vfeat, sfeat, adst, out1);

    gemm_kernel<<<dim3(MQ/32, 4), dim3(256), 0, stream>>>(out1, ffn_w1, ffn_b1, Hbuf, 128, 512, 1);
    gemm_ln2_kernel<<<dim3(MQ/32, 1), dim3(256), 0, stream>>>(Hbuf, ffn_w2, ffn_b2, out1, ln2_g, ln2_b, (float*)d_out);
}

// Round 4
// 432.838 us; speedup vs baseline: 1.7569x; 1.3425x over previous
//
#include <hip/hip_runtime.h>
#include <math.h>

#define NB 2
#define NQ 8192
#define NL 8192
#define NC 128
#define NKN 8
#define NF 512
#define MQ (NB*NQ)   // 16384 rows total (both batches)

// ===========================================================================
// Radius top-8 via uniform spatial grid, 16^3 cells per batch (lambda=2/cell).
// Pipeline: zero -> count -> scan -> scatter -> query.
// Query: 8 lanes/query scan the 5x5x5 cell block (guarantee radius 0.125);
// expand to 9x9x9 (guarantee 0.25) for the ~1% boundary queries; full scan
// as a never-taken safety net. Exact float compares, strict '<' insertion.
// ===========================================================================

__global__ __launch_bounds__(256) void grid_zero_kernel(int* __restrict__ p)
{
    int t = blockIdx.x*256 + threadIdx.x;   // 64 blocks -> 16384 ints
    p[t] = 0;
}

__device__ __forceinline__ int cell_coord(float x) {
    int c = (int)(x * 16.0f);
    return min(15, max(0, c));
}

__global__ __launch_bounds__(256) void grid_count_kernel(
    const float* __restrict__ kxyz, const unsigned char* __restrict__ pad,
    int* __restrict__ cnt)
{
    int t = blockIdx.x*256 + threadIdx.x;   // 16384 points
    if (pad[t]) return;
    int bat = t >> 13;
    float x = kxyz[t*3+0], y = kxyz[t*3+1], z = kxyz[t*3+2];
    int cell = (cell_coord(z)*16 + cell_coord(y))*16 + cell_coord(x);
    atomicAdd(&cnt[bat*4096 + cell], 1);
}

__global__ __launch_bounds__(1024) void grid_scan_kernel(
    const int* __restrict__ cnt, int* __restrict__ cs)
{
    __shared__ int wsum[17];
    int t = threadIdx.x;
    int v[8]; int s = 0;
    #pragma unroll
    for (int k = 0; k < 8; ++k) { v[k] = s; s += cnt[t*8 + k]; }
    int lane = t & 63, w = t >> 6;
    int inc = s;
    #pragma unroll
    for (int d = 1; d < 64; d <<= 1) {
        int o = __shfl_up(inc, d);
        if (lane >= d) inc += o;
    }
    if (lane == 63) wsum[w] = inc;
    __syncthreads();
    if (t == 0) {
        int a = 0;
        for (int i = 0; i < 16; ++i) { int x = wsum[i]; wsum[i] = a; a += x; }
        wsum[16] = a;
    }
    __syncthreads();
    int base = wsum[w] + (inc - s);
    #pragma unroll
    for (int k = 0; k < 8; ++k) cs[t*8 + k] = base + v[k];
    if (t == 1023) cs[8192] = wsum[16];
}

__global__ __launch_bounds__(256) void grid_scatter_kernel(
    const float* __restrict__ kxyz, const unsigned char* __restrict__ pad,
    const int* __restrict__ cs, int* __restrict__ fill, float4* __restrict__ ro)
{
    int t = blockIdx.x*256 + threadIdx.x;   // 16384 points
    if (pad[t]) return;
    int bat = t >> 13, i = t & 8191;
    float x = kxyz[t*3+0], y = kxyz[t*3+1], z = kxyz[t*3+2];
    int cell = bat*4096 + (cell_coord(z)*16 + cell_coord(y))*16 + cell_coord(x);
    int pos = cs[cell] + atomicAdd(&fill[cell], 1);
    ro[pos] = make_float4(x, y, z, __int_as_float(i));
}

__device__ __forceinline__ void insert8(float cd, int id, float dk[8], int ik[8]) {
    if (cd < dk[7]) {
        dk[7] = cd; ik[7] = id;
        #pragma unroll
        for (int r = 6; r >= 0; --r) {
            bool sw = dk[r+1] < dk[r];
            float td = dk[r]; int ti = ik[r];
            dk[r]   = sw ? dk[r+1] : dk[r];
            ik[r]   = sw ? ik[r+1] : ik[r];
            dk[r+1] = sw ? td : dk[r+1];
            ik[r+1] = sw ? ti : ik[r+1];
        }
    }
}

template<int W>
__device__ __forceinline__ void scan_block(int l, int cx, int cy, int cz,
    float qx, float qy, float qz, const int* __restrict__ CS,
    const float4* __restrict__ RO, float dk[8], int ik[8])
{
    const int D = 2*W + 1;
    int xs = max(0, cx - W), xe = min(15, cx + W);
    int nx = xe - xs + 1;
    for (int r = l; r < D*D; r += 8) {
        int dz = r / D - W, dy = r % D - W;
        int zz = cz + dz, yy = cy + dy;
        if ((unsigned)zz > 15u || (unsigned)yy > 15u) continue;
        int c0 = (zz*16 + yy)*16 + xs;
        int s = CS[c0], e = CS[c0 + nx];
        for (int p = s; p < e; ++p) {
            float4 v = RO[p];
            float dx = qx - v.x, dyv = qy - v.y, dzv = qz - v.z;
            float cd = dx*dx + dyv*dyv + dzv*dzv;
            insert8(cd, __float_as_int(v.w), dk, ik);
        }
    }
}

// bitonic merge of 8 sorted lists held by the 8 lanes of a query group
__device__ __forceinline__ void merge8(float dk[8], int ik[8]) {
    #pragma unroll
    for (int m = 1; m <= 4; m <<= 1) {
        float od[8]; int oi[8];
        #pragma unroll
        for (int r = 0; r < 8; ++r) {
            od[r] = __shfl_xor(dk[r], m);
            oi[r] = __shfl_xor(ik[r], m);
        }
        float nd[8]; int ni[8];
        #pragma unroll
        for (int r = 0; r < 8; ++r) {
            bool take = od[7-r] < dk[r];
            nd[r] = take ? od[7-r] : dk[r];
            ni[r] = take ? oi[7-r] : ik[r];
        }
        #pragma unroll
        for (int st = 4; st >= 1; st >>= 1) {
            #pragma unroll
            for (int r = 0; r < 8; ++r) {
                if ((r & st) == 0 && (r | st) < 8) {
                    int b = r | st;
                    bool sw = nd[b] < nd[r];
                    float td = nd[r]; int ti = ni[r];
                    nd[r] = sw ? nd[b] : nd[r];
                    ni[r] = sw ? ni[b] : ni[r];
                    nd[b] = sw ? td : nd[b];
                    ni[b] = sw ? ti : ni[b];
                }
            }
        }
        #pragma unroll
        for (int r = 0; r < 8; ++r) { dk[r] = nd[r]; ik[r] = ni[r]; }
    }
}

__global__ __launch_bounds__(256) void radius_grid_query_kernel(
    const float* __restrict__ qxyz, const int* __restrict__ cellstart,
    const float4* __restrict__ reorder, int* __restrict__ idxout)
{
    const int tid  = threadIdx.x;
    const int l    = tid & 7;            // lane within query group
    const int qloc = tid >> 3;           // 0..31
    const int gq   = blockIdx.x*32 + qloc;
    const int bat  = gq >> 13;
    const float qx = qxyz[gq*3+0], qy = qxyz[gq*3+1], qz = qxyz[gq*3+2];
    const int cx = cell_coord(qx), cy = cell_coord(qy), cz = cell_coord(qz);
    const int* CS = cellstart + bat*4096;
    const float R2  = (float)(0.4*0.4);
    const float R2P = __uint_as_float(__float_as_uint(R2) + 1u);

    float dk[8]; int ik[8];
    #pragma unroll
    for (int r = 0; r < 8; ++r) { dk[r] = R2P; ik[r] = -1; }

    // pass 1: 5x5x5 block, guaranteed complete if 8th-best d2 <= 0.125^2
    scan_block<2>(l, cx, cy, cz, qx, qy, qz, CS, reorder, dk, ik);
    merge8(dk, ik);
    bool done = dk[7] <= 0.015625f;

    if (!done) {   // ~1% of queries (cube corners/edges): 9x9x9, guarantee 0.25
        #pragma unroll
        for (int r = 0; r < 8; ++r) { dk[r] = R2P; ik[r] = -1; }
        scan_block<4>(l, cx, cy, cz, qx, qy, qz, CS, reorder, dk, ik);
        merge8(dk, ik);
        done = dk[7] <= 0.0625f;
    }
    if (!done) {   // safety net (never taken for uniform inputs): full scan
        #pragma unroll
        for (int r = 0; r < 8; ++r) { dk[r] = R2P; ik[r] = -1; }
        scan_block<16>(l, cx, cy, cz, qx, qy, qz, CS, reorder, dk, ik);
        merge8(dk, ik);
    }

    if (l == 0) {
        int o[8];
        #pragma unroll
        for (int r = 0; r < 8; ++r) o[r] = (dk[r] <= R2) ? ik[r] : -1;
        int4 a = {o[0], o[1], o[2], o[3]};
        int4 b = {o[4], o[5], o[6], o[7]};
        *(int4*)&idxout[(size_t)gq*8 + 0] = a;
        *(int4*)&idxout[(size_t)gq*8 + 4] = b;
    }
}

// ---------------------------------------------------------------------------
// Generic fp32 GEMM: out[M,N] = act(A[M,K] @ W[K,N] + bias)
// ---------------------------------------------------------------------------
__device__ inline float gelu_exact(float x) {
    return 0.5f*x*(1.0f + erff(x*0.7071067811865476f));
}

__global__ __launch_bounds__(256) void gemm_kernel(
    const float* __restrict__ A, const float* __restrict__ W,
    const float* __restrict__ bias, float* __restrict__ out,
    int Kd, int Nd, int act)
{
    __shared__ float a_t[32*36];
    __shared__ float w_t[32*128];
    const int tid  = threadIdx.x;
    const int row0 = blockIdx.x * 32;
    const int col0 = blockIdx.y * 128;
    const int cg = tid & 31, c0 = cg*4;
    const int rg = tid >> 5, r0 = rg*4;
    const int sr = tid >> 3, scq = (tid & 7)*4;
    float acc[4][4];
    #pragma unroll
    for (int s=0;s<4;s++)
        #pragma unroll
        for (int u=0;u<4;u++) acc[s][u]=0.f;

    const int nk = Kd >> 5;
    for (int kk = 0; kk < nk; ++kk) {
        __syncthreads();
        *(float4*)&a_t[sr*36+scq] = *(const float4*)&A[(size_t)(row0+sr)*Kd + kk*32 + scq];
        #pragma unroll
        for (int t = 0; t < 4; ++t) {
            int f4i = tid + 256*t;
            int wr = f4i >> 5, wc = (f4i & 31)*4;
            *(float4*)&w_t[wr*128+wc] = *(const float4*)&W[(size_t)(kk*32+wr)*Nd + col0 + wc];
        }
        __syncthreads();
        #pragma unroll 8
        for (int i = 0; i < 32; ++i) {
            float av[4];
            #pragma unroll
            for (int s=0;s<4;s++) av[s] = a_t[(r0+s)*36 + i];
            float4 w4 = *(float4*)&w_t[i*128 + c0];
            float wv[4] = {w4.x, w4.y, w4.z, w4.w};
            #pragma unroll
            for (int s=0;s<4;s++)
                #pragma unroll
                for (int u=0;u<4;u++) acc[s][u] += av[s]*wv[u];
        }
    }
    #pragma unroll
    for (int s = 0; s < 4; ++s) {
        float o[4];
        #pragma unroll
        for (int u=0;u<4;u++) {
            float x = acc[s][u] + (bias ? bias[col0+c0+u] : 0.f);
            o[u] = (act == 1) ? gelu_exact(x) : x;
        }
        float4 ov = {o[0], o[1], o[2], o[3]};
        *(float4*)&out[(size_t)(row0+r0+s)*Nd + col0 + c0] = ov;
    }
}

// ---------------------------------------------------------------------------
// FFN2 GEMM with fused bias + residual + LayerNorm2 epilogue.
// ---------------------------------------------------------------------------
__global__ __launch_bounds__(256) void gemm_ln2_kernel(
    const float* __restrict__ A, const float* __restrict__ W,
    const float* __restrict__ b2, const float* __restrict__ res,
    const float* __restrict__ g, const float* __restrict__ bb,
    float* __restrict__ out)
{
    __shared__ float a_t[32*36];
    __shared__ float w_t[32*128];
    const int tid  = threadIdx.x;
    const int row0 = blockIdx.x * 32;
    const int cg = tid & 31, c0 = cg*4;
    const int rg = tid >> 5, r0 = rg*4;
    const int sr = tid >> 3, scq = (tid & 7)*4;
    float acc[4][4];
    #pragma unroll
    for (int s=0;s<4;s++)
        #pragma unroll
        for (int u=0;u<4;u++) acc[s][u]=0.f;

    for (int kk = 0; kk < 16; ++kk) {
        __syncthreads();
        *(float4*)&a_t[sr*36+scq] = *(const float4*)&A[(size_t)(row0+sr)*NF + kk*32 + scq];
        #pragma unroll
        for (int t = 0; t < 4; ++t) {
            int f4i = tid + 256*t;
            int wr = f4i >> 5, wc = (f4i & 31)*4;
            *(float4*)&w_t[wr*128+wc] = *(const float4*)&W[(size_t)(kk*32+wr)*NC + wc];
        }
        __syncthreads();
        #pragma unroll 8
        for (int i = 0; i < 32; ++i) {
            float av[4];
            #pragma unroll
            for (int s=0;s<4;s++) av[s] = a_t[(r0+s)*36 + i];
            float4 w4 = *(float4*)&w_t[i*128 + c0];
            float wv[4] = {w4.x, w4.y, w4.z, w4.w};
            #pragma unroll
            for (int s=0;s<4;s++)
                #pragma unroll
                for (int u=0;u<4;u++) acc[s][u] += av[s]*wv[u];
        }
    }
    float x[4][4];
    #pragma unroll
    for (int s=0;s<4;s++)
        #pragma unroll
        for (int u=0;u<4;u++)
            x[s][u] = acc[s][u] + b2[c0+u] + res[(size_t)(row0+r0+s)*NC + c0 + u];

    float sm[4];
    #pragma unroll
    for (int s=0;s<4;s++) sm[s] = x[s][0]+x[s][1]+x[s][2]+x[s][3];
    #pragma unroll
    for (int m = 1; m <= 16; m <<= 1)
        #pragma unroll
        for (int s=0;s<4;s++) sm[s] += __shfl_xor(sm[s], m);
    float mean[4];
    #pragma unroll
    for (int s=0;s<4;s++) mean[s] = sm[s]*(1.0f/128.0f);

    float vv[4];
    #pragma unroll
    for (int s=0;s<4;s++) {
        vv[s]=0.f;
        #pragma unroll
        for (int u=0;u<4;u++) { float d = x[s][u]-mean[s]; vv[s] += d*d; }
    }
    #pragma unroll
    for (int m = 1; m <= 16; m <<= 1)
        #pragma unroll
        for (int s=0;s<4;s++) vv[s] += __shfl_xor(vv[s], m);

    #pragma unroll
    for (int s=0;s<4;s++) {
        float rstd = rsqrtf(vv[s]*(1.0f/128.0f) + 1e-5f);
        float o[4];
        #pragma unroll
        for (int u=0;u<4;u++)
            o[u] = (x[s][u]-mean[s])*rstd*g[c0+u] + bb[c0+u];
        float4 ov = {o[0],o[1],o[2],o[3]};
        *(float4*)&out[(size_t)(row0+r0+s)*NC + c0] = ov;
    }
}

// ---------------------------------------------------------------------------
// Fused per-edge attention (unchanged from round 3).
// ---------------------------------------------------------------------------
__global__ __launch_bounds__(128) void attn_fused_kernel(
    const float* __restrict__ qxyz, const float* __restrict__ qfeat,
    const float* __restrict__ kxyz,
    const float* __restrict__ posw1, const float* __restrict__ posb1,
    const float* __restrict__ posw2, const float* __restrict__ posb2,
    const float* __restrict__ attnw, const float* __restrict__ attnb,
    const float* __restrict__ ln1g, const float* __restrict__ ln1b,
    const int* __restrict__ idx, const float* __restrict__ vfeat,
    const float* __restrict__ sfeat, const float* __restrict__ adst,
    float* __restrict__ out1)
{
    __shared__ float ws_w[32*128];
    __shared__ float ws_a[64*132];
    __shared__ float s_w1[3*128];
    __shared__ float s_b1[128], s_b2[128], s_ab[128], s_g[128], s_bb[128];
    __shared__ float s_rx[64], s_ry[64], s_rz[64];
    __shared__ int   s_j[64];

    const int tid = threadIdx.x;
    const int cw = tid & 7, c0 = cw*16;
    const int ew = tid >> 3;
    const int e0 = ew*4;
    const int ql = ew >> 1;
    const int q0 = blockIdx.x * 8;
    const int bat = q0 >> 13;
    const int gq = q0 + ql;

    {
        int i = tid;
        s_b1[i]=posb1[i]; s_b2[i]=posb2[i]; s_ab[i]=attnb[i];
        s_g[i]=ln1g[i];   s_bb[i]=ln1b[i];
        s_w1[i]=posw1[i]; s_w1[128+i]=posw1[128+i]; s_w1[256+i]=posw1[256+i];
    }
    if (tid < 64) {
        int q = q0 + (tid >> 3);
        int j = idx[(size_t)q0*8 + tid];
        s_j[tid] = j;
        int jc = j < 0 ? 0 : j;
        const float* kp = kxyz + ((size_t)(bat*NL + jc))*3;
        s_rx[tid] = qxyz[q*3+0] - kp[0];
        s_ry[tid] = qxyz[q*3+1] - kp[1];
        s_rz[tid] = qxyz[q*3+2] - kp[2];
    }
    __syncthreads();

    {
        float rx[4], ry[4], rz[4];
        #pragma unroll
        for (int s=0;s<4;s++){ rx[s]=s_rx[e0+s]; ry[s]=s_ry[e0+s]; rz[s]=s_rz[e0+s]; }
        #pragma unroll
        for (int s=0;s<4;s++)
            #pragma unroll
            for (int c=0;c<16;c++){
                int cc = c0+c;
                float h = s_b1[cc] + rx[s]*s_w1[cc] + ry[s]*s_w1[128+cc] + rz[s]*s_w1[256+cc];
                ws_a[(e0+s)*132+cc] = fmaxf(h, 0.0f);
            }
    }

    float acc[4][16];
    #pragma unroll
    for (int s=0;s<4;s++)
        #pragma unroll
        for (int c=0;c<16;c++) acc[s][c]=0.f;

    for (int kk = 0; kk < 4; ++kk) {
        __syncthreads();
        const float* wsrc = posw2 + (size_t)kk*32*128;
        #pragma unroll
        for (int t=0;t<8;t++){
            int off = (tid + t*128)*4;
            *(float4*)&ws_w[off] = *(const float4*)&wsrc[off];
        }
        __syncthreads();
        #pragma unroll 4
        for (int i = 0; i < 32; ++i) {
            float av[4];
            #pragma unroll
            for (int s=0;s<4;s++) av[s] = ws_a[(e0+s)*132 + kk*32 + i];
            float wv[16];
            *(float4*)&wv[0]  = *(float4*)&ws_w[i*128 + c0 + 0];
            *(float4*)&wv[4]  = *(float4*)&ws_w[i*128 + c0 + 4];
            *(float4*)&wv[8]  = *(float4*)&ws_w[i*128 + c0 + 8];
            *(float4*)&wv[12] = *(float4*)&ws_w[i*128 + c0 + 12];
            #pragma unroll
            for (int s=0;s<4;s++)
                #pragma unroll
                for (int c=0;c<16;c++) acc[s][c] += av[s]*wv[c];
        }
    }

    float delta[4][16];
    #pragma unroll
    for (int s=0;s<4;s++)
        #pragma unroll
        for (int c=0;c<16;c++) delta[s][c] = fmaxf(acc[s][c] + s_b2[c0+c], 0.f);

    __syncthreads();

    int jr[4];
    #pragma unroll
    for (int s=0;s<4;s++){ int j = s_j[e0+s]; jr[s] = j < 0 ? 0 : j; }
    {
        float ad[16];
        const float* ap = adst + (size_t)gq*NC + c0;
        *(float4*)&ad[0]  = *(const float4*)&ap[0];
        *(float4*)&ad[4]  = *(const float4*)&ap[4];
        *(float4*)&ad[8]  = *(const float4*)&ap[8];
        *(float4*)&ad[12] = *(const float4*)&ap[12];
        #pragma unroll
        for (int s=0;s<4;s++){
            const float* sp = sfeat + ((size_t)(bat*NL + jr[s]))*NC + c0;
            #pragma unroll
            for (int u=0;u<4;u++){
                float4 sv = *(const float4*)&sp[4*u];
                float4 tv;
                tv.x = ad[4*u+0] - sv.x + delta[s][4*u+0];
                tv.y = ad[4*u+1] - sv.y + delta[s][4*u+1];
                tv.z = ad[4*u+2] - sv.z + delta[s][4*u+2];
                tv.w = ad[4*u+3] - sv.w + delta[s][4*u+3];
                *(float4*)&ws_a[(e0+s)*132 + c0 + 4*u] = tv;
            }
        }
    }

    #pragma unroll
    for (int s=0;s<4;s++)
        #pragma unroll
        for (int c=0;c<16;c++) acc[s][c]=0.f;

    for (int kk = 0; kk < 4; ++kk) {
        __syncthreads();
        const float* wsrc = attnw + (size_t)kk*32*128;
        #pragma unroll
        for (int t=0;t<8;t++){
            int off = (tid + t*128)*4;
            *(float4*)&ws_w[off] = *(const float4*)&wsrc[off];
        }
        __syncthreads();
        #pragma unroll 4
        for (int i = 0; i < 32; ++i) {
            float av[4];
            #pragma unroll
            for (int s=0;s<4;s++) av[s] = ws_a[(e0+s)*132 + kk*32 + i];
            float wv[16];
            *(float4*)&wv[0]  = *(float4*)&ws_w[i*128 + c0 + 0];
            *(float4*)&wv[4]  = *(float4*)&ws_w[i*128 + c0 + 4];
            *(float4*)&wv[8]  = *(float4*)&ws_w[i*128 + c0 + 8];
            *(float4*)&wv[12] = *(float4*)&ws_w[i*128 + c0 + 12];
            #pragma unroll
            for (int s=0;s<4;s++)
                #pragma unroll
                for (int c=0;c<16;c++) acc[s][c] += av[s]*wv[c];
        }
    }

    bool val[4];
    #pragma unroll
    for (int s=0;s<4;s++) val[s] = (s_j[e0+s] >= 0);
    float sc[4][16];
    #pragma unroll
    for (int s=0;s<4;s++)
        #pragma unroll
        for (int c=0;c<16;c++){
            float a = fmaxf(acc[s][c] + s_ab[c0+c], 0.f);
            sc[s][c] = val[s] ? a : -INFINITY;
        }

    float mx[16], dnm[16];
    #pragma unroll
    for (int c=0;c<16;c++){
        float m = fmaxf(fmaxf(sc[0][c], sc[1][c]), fmaxf(sc[2][c], sc[3][c]));
        m = fmaxf(m, __shfl_xor(m, 8));
        if (m == -INFINITY) m = 0.f;
        mx[c] = m;
    }
    #pragma unroll
    for (int s=0;s<4;s++)
        #pragma unroll
        for (int c=0;c<16;c++)
            sc[s][c] = val[s] ? expf(sc[s][c] - mx[c]) : 0.f;
    #pragma unroll
    for (int c=0;c<16;c++){
        float sum = sc[0][c]+sc[1][c]+sc[2][c]+sc[3][c];
        sum += __shfl_xor(sum, 8);
        dnm[c] = fmaxf(sum, 1e-12f);
    }

    float part[16];
    #pragma unroll
    for (int c=0;c<16;c++) part[c]=0.f;
    #pragma unroll
    for (int s=0;s<4;s++){
        const float* vp = vfeat + ((size_t)(bat*NL + jr[s]))*NC + c0;
        #pragma unroll
        for (int u=0;u<4;u++){
            float4 xv = *(const float4*)&vp[4*u];
            part[4*u+0] += sc[s][4*u+0]*(xv.x + delta[s][4*u+0]);
            part[4*u+1] += sc[s][4*u+1]*(xv.y + delta[s][4*u+1]);
            part[4*u+2] += sc[s][4*u+2]*(xv.z + delta[s][4*u+2]);
            part[4*u+3] += sc[s][4*u+3]*(xv.w + delta[s][4*u+3]);
        }
    }
    float xln[16];
    {
        const float* qp = qfeat + (size_t)gq*NC + c0;
        #pragma unroll
        for (int c=0;c<16;c++){
            float agg = part[c]/dnm[c];
            agg += __shfl_xor(agg, 8);
            xln[c] = qp[c] + agg;
        }
    }
    float sm = 0.f;
    #pragma unroll
    for (int c=0;c<16;c++) sm += xln[c];
    #pragma unroll
    for (int m = 1; m <= 8; m <<= 1) sm += __shfl_xor(sm, m);
    float mean = sm*(1.0f/256.0f);
    float vv = 0.f;
    #pragma unroll
    for (int c=0;c<16;c++){ float d = xln[c]-mean; vv += d*d; }
    #pragma unroll
    for (int m = 1; m <= 8; m <<= 1) vv += __shfl_xor(vv, m);
    float rstd = rsqrtf(vv*(1.0f/256.0f) + 1e-5f);

    if ((ew & 1) == 0) {
        float* op = out1 + (size_t)gq*NC + c0;
        #pragma unroll
        for (int u=0;u<4;u++){
            float4 ov;
            ov.x = (xln[4*u+0]-mean)*rstd*s_g[c0+4*u+0] + s_bb[c0+4*u+0];
            ov.y = (xln[4*u+1]-mean)*rstd*s_g[c0+4*u+1] + s_bb[c0+4*u+1];
            ov.z = (xln[4*u+2]-mean)*rstd*s_g[c0+4*u+2] + s_bb[c0+4*u+2];
            ov.w = (xln[4*u+3]-mean)*rstd*s_g[c0+4*u+3] + s_bb[c0+4*u+3];
            *(float4*)&op[4*u] = ov;
        }
    }
}

// ---------------------------------------------------------------------------
extern "C" void kernel_launch(void* const* d_in, const int* in_sizes, int n_in,
                              void* d_out, int out_size, void* d_ws, size_t ws_size,
                              hipStream_t stream)
{
    (void)in_sizes; (void)n_in; (void)out_size; (void)ws_size;
    const float* q_xyz   = (const float*)d_in[0];
    const float* q_feat  = (const float*)d_in[1];
    const float* kv_xyz  = (const float*)d_in[2];
    const float* kv_feat = (const float*)d_in[3];
    const unsigned char* kv_pad = (const unsigned char*)d_in[4];
    const float* pos_w1  = (const float*)d_in[5];
    const float* pos_b1  = (const float*)d_in[6];
    const float* pos_w2  = (const float*)d_in[7];
    const float* pos_b2  = (const float*)d_in[8];
    const float* attn_w  = (const float*)d_in[9];
    const float* attn_b  = (const float*)d_in[10];
    const float* lin_w   = (const float*)d_in[11];
    const float* lin_src_w = (const float*)d_in[12];
    const float* lin_dst_w = (const float*)d_in[13];
    const float* ln1_g   = (const float*)d_in[14];
    const float* ln1_b   = (const float*)d_in[15];
    const float* ffn_w1  = (const float*)d_in[16];
    const float* ffn_b1  = (const float*)d_in[17];
    const float* ffn_w2  = (const float*)d_in[18];
    const float* ffn_b2  = (const float*)d_in[19];
    const float* ln2_g   = (const float*)d_in[20];
    const float* ln2_b   = (const float*)d_in[21];

    float* ws    = (float*)d_ws;
    int*   idx   = (int*)d_ws;                       // MQ*8 ints
    float* vfeat = ws + 131072;                      // [MQ, 128]
    float* sfeat = vfeat + (size_t)MQ*NC;            // [MQ, 128]
    float* adst  = sfeat + (size_t)MQ*NC;            // [MQ, 128]
    float* out1  = adst  + (size_t)MQ*NC;            // [MQ, 128]
    float* Hbuf  = out1  + (size_t)MQ*NC;            // [MQ, 512]

    // grid-build scratch overlaid on Hbuf (dead until FFN1, which runs after)
    float4* reorder  = (float4*)Hbuf;                // 16384 float4
    int* cellcnt   = (int*)(reorder + 16384);        // 8192
    int* cellfill  = cellcnt + 8192;                 // 8192
    int* cellstart = cellfill + 8192;                // 8193

    grid_zero_kernel<<<dim3(64), dim3(256), 0, stream>>>(cellcnt);   // zeroes cnt+fill (16384 ints)
    grid_count_kernel<<<dim3(64), dim3(256), 0, stream>>>(kv_xyz, kv_pad, cellcnt);
    grid_scan_kernel<<<dim3(1), dim3(1024), 0, stream>>>(cellcnt, cellstart);
    grid_scatter_kernel<<<dim3(64), dim3(256), 0, stream>>>(kv_xyz, kv_pad, cellstart, cellfill, reorder);
    radius_grid_query_kernel<<<dim3(MQ/32), dim3(256), 0, stream>>>(q_xyz, cellstart, reorder, idx);

    gemm_kernel<<<dim3(MQ/32, 1), dim3(256), 0, stream>>>(kv_feat, lin_w,     nullptr, vfeat, 128, 128, 0);
    gemm_kernel<<<dim3(MQ/32, 1), dim3(256), 0, stream>>>(kv_feat, lin_src_w, nullptr, sfeat, 128, 128, 0);
    gemm_kernel<<<dim3(MQ/32, 1), dim3(256), 0, stream>>>(q_feat,  lin_dst_w, nullptr, adst,  128, 128, 0);

    attn_fused_kernel<<<dim3(MQ/8), dim3(128), 0, stream>>>(
        q_xyz, q_feat, kv_xyz,
        pos_w1, pos_b1, pos_w2, pos_b2, attn_w, attn_b,
        ln1_g, ln1_b, idx, vfeat, sfeat, adst, out1);

    gemm_kernel<<<dim3(MQ/32, 4), dim3(256), 0, stream>>>(out1, ffn_w1, ffn_b1, Hbuf, 128, 512, 1);
    gemm_ln2_kernel<<<dim3(MQ/32, 1), dim3(256), 0, stream>>>(Hbuf, ffn_w2, ffn_b2, out1, ln2_g, ln2_b, (float*)d_out);
}

// Round 5
// 321.198 us; speedup vs baseline: 2.3675x; 1.3476x over previous
//
#include <hip/hip_runtime.h>
#include <math.h>

#define NB 2
#define NQ 8192
#define NL 8192
#define NC 128
#define NKN 8
#define NF 512
#define MQ (NB*NQ)   // 16384 rows total (both batches)

typedef __attribute__((ext_vector_type(8))) short bf16x8;
typedef __attribute__((ext_vector_type(4))) float f32x4;

__device__ __forceinline__ unsigned short f2bf_u(float f){
    unsigned u = __float_as_uint(f);
    return (unsigned short)((u + 0x7FFFu + ((u>>16)&1u)) >> 16);
}

// ===========================================================================
// Radius top-8 via uniform spatial grid, 16^3 cells per batch (lambda=2/cell).
// ===========================================================================

__global__ __launch_bounds__(256) void grid_zero_kernel(int* __restrict__ p)
{
    int t = blockIdx.x*256 + threadIdx.x;   // 64 blocks -> 16384 ints
    p[t] = 0;
}

__device__ __forceinline__ int cell_coord(float x) {
    int c = (int)(x * 16.0f);
    return min(15, max(0, c));
}

__global__ __launch_bounds__(256) void grid_count_kernel(
    const float* __restrict__ kxyz, const unsigned char* __restrict__ pad,
    int* __restrict__ cnt)
{
    int t = blockIdx.x*256 + threadIdx.x;   // 16384 points
    if (pad[t]) return;
    int bat = t >> 13;
    float x = kxyz[t*3+0], y = kxyz[t*3+1], z = kxyz[t*3+2];
    int cell = (cell_coord(z)*16 + cell_coord(y))*16 + cell_coord(x);
    atomicAdd(&cnt[bat*4096 + cell], 1);
}

__global__ __launch_bounds__(1024) void grid_scan_kernel(
    const int* __restrict__ cnt, int* __restrict__ cs)
{
    __shared__ int wsum[17];
    int t = threadIdx.x;
    int v[8]; int s = 0;
    #pragma unroll
    for (int k = 0; k < 8; ++k) { v[k] = s; s += cnt[t*8 + k]; }
    int lane = t & 63, w = t >> 6;
    int inc = s;
    #pragma unroll
    for (int d = 1; d < 64; d <<= 1) {
        int o = __shfl_up(inc, d);
        if (lane >= d) inc += o;
    }
    if (lane == 63) wsum[w] = inc;
    __syncthreads();
    if (t == 0) {
        int a = 0;
        for (int i = 0; i < 16; ++i) { int x = wsum[i]; wsum[i] = a; a += x; }
        wsum[16] = a;
    }
    __syncthreads();
    int base = wsum[w] + (inc - s);
    #pragma unroll
    for (int k = 0; k < 8; ++k) cs[t*8 + k] = base + v[k];
    if (t == 1023) cs[8192] = wsum[16];
}

__global__ __launch_bounds__(256) void grid_scatter_kernel(
    const float* __restrict__ kxyz, const unsigned char* __restrict__ pad,
    const int* __restrict__ cs, int* __restrict__ fill, float4* __restrict__ ro)
{
    int t = blockIdx.x*256 + threadIdx.x;   // 16384 points
    if (pad[t]) return;
    int bat = t >> 13, i = t & 8191;
    float x = kxyz[t*3+0], y = kxyz[t*3+1], z = kxyz[t*3+2];
    int cell = bat*4096 + (cell_coord(z)*16 + cell_coord(y))*16 + cell_coord(x);
    int pos = cs[cell] + atomicAdd(&fill[cell], 1);
    ro[pos] = make_float4(x, y, z, __int_as_float(i));
}

__device__ __forceinline__ void insert8(float cd, int id, float dk[8], int ik[8]) {
    if (cd < dk[7]) {
        dk[7] = cd; ik[7] = id;
        #pragma unroll
        for (int r = 6; r >= 0; --r) {
            bool sw = dk[r+1] < dk[r];
            float td = dk[r]; int ti = ik[r];
            dk[r]   = sw ? dk[r+1] : dk[r];
            ik[r]   = sw ? ik[r+1] : ik[r];
            dk[r+1] = sw ? td : dk[r+1];
            ik[r+1] = sw ? ti : ik[r+1];
        }
    }
}

template<int W>
__device__ __forceinline__ void scan_block(int l, int cx, int cy, int cz,
    float qx, float qy, float qz, const int* __restrict__ CS,
    const float4* __restrict__ RO, float dk[8], int ik[8])
{
    const int D = 2*W + 1;
    int xs = max(0, cx - W), xe = min(15, cx + W);
    int nx = xe - xs + 1;
    for (int r = l; r < D*D; r += 8) {
        int dz = r / D - W, dy = r % D - W;
        int zz = cz + dz, yy = cy + dy;
        if ((unsigned)zz > 15u || (unsigned)yy > 15u) continue;
        int c0 = (zz*16 + yy)*16 + xs;
        int s = CS[c0], e = CS[c0 + nx];
        for (int p = s; p < e; ++p) {
            float4 v = RO[p];
            float dx = qx - v.x, dyv = qy - v.y, dzv = qz - v.z;
            float cd = dx*dx + dyv*dyv + dzv*dzv;
            insert8(cd, __float_as_int(v.w), dk, ik);
        }
    }
}

__device__ __forceinline__ void merge8(float dk[8], int ik[8]) {
    #pragma unroll
    for (int m = 1; m <= 4; m <<= 1) {
        float od[8]; int oi[8];
        #pragma unroll
        for (int r = 0; r < 8; ++r) {
            od[r] = __shfl_xor(dk[r], m);
            oi[r] = __shfl_xor(ik[r], m);
        }
        float nd[8]; int ni[8];
        #pragma unroll
        for (int r = 0; r < 8; ++r) {
            bool take = od[7-r] < dk[r];
            nd[r] = take ? od[7-r] : dk[r];
            ni[r] = take ? oi[7-r] : ik[r];
        }
        #pragma unroll
        for (int st = 4; st >= 1; st >>= 1) {
            #pragma unroll
            for (int r = 0; r < 8; ++r) {
                if ((r & st) == 0 && (r | st) < 8) {
                    int b = r | st;
                    bool sw = nd[b] < nd[r];
                    float td = nd[r]; int ti = ni[r];
                    nd[r] = sw ? nd[b] : nd[r];
                    ni[r] = sw ? ni[b] : ni[r];
                    nd[b] = sw ? td : nd[b];
                    ni[b] = sw ? ti : ni[b];
                }
            }
        }
        #pragma unroll
        for (int r = 0; r < 8; ++r) { dk[r] = nd[r]; ik[r] = ni[r]; }
    }
}

__global__ __launch_bounds__(256) void radius_grid_query_kernel(
    const float* __restrict__ qxyz, const int* __restrict__ cellstart,
    const float4* __restrict__ reorder, int* __restrict__ idxout)
{
    const int tid  = threadIdx.x;
    const int l    = tid & 7;
    const int qloc = tid >> 3;
    const int gq   = blockIdx.x*32 + qloc;
    const int bat  = gq >> 13;
    const float qx = qxyz[gq*3+0], qy = qxyz[gq*3+1], qz = qxyz[gq*3+2];
    const int cx = cell_coord(qx), cy = cell_coord(qy), cz = cell_coord(qz);
    const int* CS = cellstart + bat*4096;
    const float R2  = (float)(0.4*0.4);
    const float R2P = __uint_as_float(__float_as_uint(R2) + 1u);

    float dk[8]; int ik[8];
    #pragma unroll
    for (int r = 0; r < 8; ++r) { dk[r] = R2P; ik[r] = -1; }

    scan_block<2>(l, cx, cy, cz, qx, qy, qz, CS, reorder, dk, ik);
    merge8(dk, ik);
    bool done = dk[7] <= 0.015625f;

    if (!done) {
        #pragma unroll
        for (int r = 0; r < 8; ++r) { dk[r] = R2P; ik[r] = -1; }
        scan_block<4>(l, cx, cy, cz, qx, qy, qz, CS, reorder, dk, ik);
        merge8(dk, ik);
        done = dk[7] <= 0.0625f;
    }
    if (!done) {
        #pragma unroll
        for (int r = 0; r < 8; ++r) { dk[r] = R2P; ik[r] = -1; }
        scan_block<16>(l, cx, cy, cz, qx, qy, qz, CS, reorder, dk, ik);
        merge8(dk, ik);
    }

    if (l == 0) {
        int o[8];
        #pragma unroll
        for (int r = 0; r < 8; ++r) o[r] = (dk[r] <= R2) ? ik[r] : -1;
        int4 a = {o[0], o[1], o[2], o[3]};
        int4 b = {o[4], o[5], o[6], o[7]};
        *(int4*)&idxout[(size_t)gq*8 + 0] = a;
        *(int4*)&idxout[(size_t)gq*8 + 4] = b;
    }
}

// ===========================================================================
// Weight prep: fp32 W[128][128] ([k][c] row-major) -> bf16 LDS-image:
// 4 chunks (kk) x [c=0..127 rows, stride 80B] x [k_local 0..31 bf16].
// Row stride 80B makes the b128 frag reads bank-uniform (8 touches/bank).
// ===========================================================================
__global__ __launch_bounds__(256) void wprep_kernel(
    const float* __restrict__ wA, const float* __restrict__ wB,
    unsigned short* __restrict__ imgA, unsigned short* __restrict__ imgB)
{
    int t = blockIdx.x*256 + threadIdx.x;   // 16384 = 128x128
    int k = t >> 7, c = t & 127;
    int off = (k >> 5)*5120 + c*40 + (k & 31);   // ushort units (10240B chunk, 80B row)
    imgA[off] = f2bf_u(wA[t]);
    imgB[off] = f2bf_u(wB[t]);
}

// ===========================================================================
// Fused per-edge attention via bf16 MFMA 16x16x32.
// 256 threads = 4 waves; 16 edges/wave (2 queries); 8 queries/block.
// GEMM1: delta_pre = h1 @ posw2 (h1 built in A-frag registers).
// GEMM2: alpha_pre = T @ attnw  (T via per-wave LDS round trip).
// Epilogue: relu/mask -> softmax over K=8 (4 in-reg + shfl_xor 16) ->
// agg -> residual -> LN1 -> out1.
// ===========================================================================
__global__ __launch_bounds__(256) void attn_mfma_kernel(
    const float* __restrict__ qxyz, const float* __restrict__ qfeat,
    const float* __restrict__ kxyz,
    const float* __restrict__ posw1, const float* __restrict__ posb1,
    const float* __restrict__ posb2, const float* __restrict__ attnb,
    const float* __restrict__ ln1g, const float* __restrict__ ln1b,
    const unsigned short* __restrict__ wimg1, const unsigned short* __restrict__ wimg2,
    const int* __restrict__ idx, const float* __restrict__ vfeat,
    const float* __restrict__ sfeat, const float* __restrict__ adst,
    float* __restrict__ out1)
{
    __shared__ int4 s_wc[640];          // 10240B shared weight chunk
    __shared__ int4 s_t4[1088];         // 4 waves x 16 rows x 272B T tiles
    __shared__ float s_w1[384];
    __shared__ float s_b1[128], s_b2[128], s_ab[128], s_g[128], s_bb[128];
    __shared__ int   s_j[64];

    const int tid  = threadIdx.x;
    const int w    = tid >> 6;
    const int lane = tid & 63;
    const int l15  = lane & 15;
    const int quad = lane >> 4;
    const int qbase = blockIdx.x*8 + w*2;
    const int bat  = (blockIdx.x*8) >> 13;   // block never straddles batches

    if (tid < 128) {
        s_b1[tid] = posb1[tid]; s_b2[tid] = posb2[tid];
        s_ab[tid] = attnb[tid]; s_g[tid] = ln1g[tid]; s_bb[tid] = ln1b[tid];
    } else {
        int i = tid - 128;
        s_w1[i] = posw1[i]; s_w1[128+i] = posw1[128+i]; s_w1[256+i] = posw1[256+i];
    }
    if (tid < 64) s_j[tid] = idx[(size_t)blockIdx.x*64 + tid];
    __syncthreads();

    // --- h1 A-fragments: lane = edge l15, channels kk*32 + quad*8 + j ---
    bf16x8 h1f[4];
    {
        int e  = w*16 + l15;
        int qh = qbase + (l15 >> 3);
        int j  = s_j[e];
        int jc = j < 0 ? 0 : j;
        const float* kp = kxyz + ((size_t)(bat*NL + jc))*3;
        float rx = qxyz[qh*3+0]-kp[0], ry = qxyz[qh*3+1]-kp[1], rz = qxyz[qh*3+2]-kp[2];
        #pragma unroll
        for (int kk=0;kk<4;kk++){
            #pragma unroll
            for (int jj=0;jj<8;jj++){
                int c = kk*32 + quad*8 + jj;
                float h = s_b1[c] + rx*s_w1[c] + ry*s_w1[128+c] + rz*s_w1[256+c];
                h = fmaxf(h, 0.f);
                h1f[kk][jj] = (short)f2bf_u(h);
            }
        }
    }

    // --- GEMM1: delta_pre ---
    f32x4 acc[8];
    #pragma unroll
    for (int t=0;t<8;t++){ acc[t][0]=0.f; acc[t][1]=0.f; acc[t][2]=0.f; acc[t][3]=0.f; }

    for (int kk=0;kk<4;kk++){
        __syncthreads();
        const int4* src = (const int4*)(wimg1 + (size_t)kk*5120);
        #pragma unroll
        for (int r=0;r<3;r++){
            int o = r*256 + tid;
            if (o < 640) s_wc[o] = src[o];
        }
        __syncthreads();
        const char* wb = (const char*)s_wc;
        #pragma unroll
        for (int t=0;t<8;t++){
            bf16x8 wf = *(const bf16x8*)(wb + (16*t + l15)*80 + quad*16);
            acc[t] = __builtin_amdgcn_mfma_f32_16x16x32_bf16(h1f[kk], wf, acc[t], 0, 0, 0);
        }
    }

    // delta in C-layout: dreg[t][r] = delta[e=quad*4+r][c=16t+l15]
    f32x4 dreg[8];
    #pragma unroll
    for (int t=0;t<8;t++){
        float b2v = s_b2[16*t + l15];
        #pragma unroll
        for (int r=0;r<4;r++) dreg[t][r] = fmaxf(acc[t][r] + b2v, 0.f);
    }

    // --- T = adst - a_src + delta, bf16, to per-wave LDS tile ---
    int jr[4]; bool val[4];
    #pragma unroll
    for (int r=0;r<4;r++){
        int j = s_j[w*16 + quad*4 + r];
        val[r] = (j >= 0); jr[r] = j < 0 ? 0 : j;
    }
    const int qt = qbase + (quad >> 1);
    char* st = (char*)s_t4 + w*4352;
    #pragma unroll
    for (int t=0;t<8;t++){
        float ad = adst[(size_t)qt*NC + 16*t + l15];
        #pragma unroll
        for (int r=0;r<4;r++){
            float sv = sfeat[((size_t)(bat*NL + jr[r]))*NC + 16*t + l15];
            float tv = ad - sv + dreg[t][r];
            *(unsigned short*)(st + (quad*4+r)*272 + (16*t+l15)*2) = f2bf_u(tv);
        }
    }

    // --- GEMM2: alpha_pre ---
    f32x4 acc2[8];
    #pragma unroll
    for (int t=0;t<8;t++){ acc2[t][0]=0.f; acc2[t][1]=0.f; acc2[t][2]=0.f; acc2[t][3]=0.f; }

    for (int kk=0;kk<4;kk++){
        __syncthreads();   // also orders T writes (full waitcnt) before frag reads
        const int4* src = (const int4*)(wimg2 + (size_t)kk*5120);
        #pragma unroll
        for (int r=0;r<3;r++){
            int o = r*256 + tid;
            if (o < 640) s_wc[o] = src[o];
        }
        __syncthreads();
        bf16x8 tf = *(const bf16x8*)(st + l15*272 + kk*64 + quad*16);
        const char* wb = (const char*)s_wc;
        #pragma unroll
        for (int t=0;t<8;t++){
            bf16x8 wf = *(const bf16x8*)(wb + (16*t + l15)*80 + quad*16);
            acc2[t] = __builtin_amdgcn_mfma_f32_16x16x32_bf16(tf, wf, acc2[t], 0, 0, 0);
        }
    }

    // --- softmax over the 8 edges of each query, per channel ---
    float ex[8][4]; float dnm[8];
    #pragma unroll
    for (int t=0;t<8;t++){
        float ab = s_ab[16*t + l15];
        float s0 = val[0] ? fmaxf(acc2[t][0] + ab, 0.f) : -INFINITY;
        float s1 = val[1] ? fmaxf(acc2[t][1] + ab, 0.f) : -INFINITY;
        float s2 = val[2] ? fmaxf(acc2[t][2] + ab, 0.f) : -INFINITY;
        float s3 = val[3] ? fmaxf(acc2[t][3] + ab, 0.f) : -INFINITY;
        float mx = fmaxf(fmaxf(s0,s1), fmaxf(s2,s3));
        mx = fmaxf(mx, __shfl_xor(mx, 16));
        if (mx < -1e37f) mx = 0.f;
        ex[t][0] = __expf(s0 - mx);
        ex[t][1] = __expf(s1 - mx);
        ex[t][2] = __expf(s2 - mx);
        ex[t][3] = __expf(s3 - mx);
        float sm = ex[t][0]+ex[t][1]+ex[t][2]+ex[t][3];
        sm += __shfl_xor(sm, 16);
        dnm[t] = fmaxf(sm, 1e-12f);
    }

    // --- agg = sum_e attn * (x_j + delta) ---
    float part[8];
    #pragma unroll
    for (int t=0;t<8;t++){
        float p = 0.f;
        #pragma unroll
        for (int r=0;r<4;r++){
            float vv = vfeat[((size_t)(bat*NL + jr[r]))*NC + 16*t + l15];
            p += ex[t][r] * (vv + dreg[t][r]);
        }
        p += __shfl_xor(p, 16);
        part[t] = p / dnm[t];
    }

    // --- residual + LN1 ---
    float xln[8];
    float S = 0.f;
    #pragma unroll
    for (int t=0;t<8;t++){
        xln[t] = qfeat[(size_t)qt*NC + 16*t + l15] + part[t];
        S += xln[t];
    }
    #pragma unroll
    for (int m=1;m<=8;m<<=1) S += __shfl_xor(S, m);
    float mean = S * (1.f/128.f);
    float V = 0.f;
    #pragma unroll
    for (int t=0;t<8;t++){ float d = xln[t]-mean; V += d*d; }
    #pragma unroll
    for (int m=1;m<=8;m<<=1) V += __shfl_xor(V, m);
    float rstd = rsqrtf(V*(1.f/128.f) + 1e-5f);

    if ((quad & 1) == 0){
        #pragma unroll
        for (int t=0;t<8;t++){
            int c = 16*t + l15;
            out1[(size_t)qt*NC + c] = (xln[t]-mean)*rstd*s_g[c] + s_bb[c];
        }
    }
}

// ---------------------------------------------------------------------------
// Generic fp32 GEMM: out[M,N] = act(A[M,K] @ W[K,N] + bias)
// ---------------------------------------------------------------------------
__device__ inline float gelu_exact(float x) {
    return 0.5f*x*(1.0f + erff(x*0.7071067811865476f));
}

__global__ __launch_bounds__(256) void gemm_kernel(
    const float* __restrict__ A, const float* __restrict__ W,
    const float* __restrict__ bias, float* __restrict__ out,
    int Kd, int Nd, int act)
{
    __shared__ float a_t[32*36];
    __shared__ float w_t[32*128];
    const int tid  = threadIdx.x;
    const int row0 = blockIdx.x * 32;
    const int col0 = blockIdx.y * 128;
    const int cg = tid & 31, c0 = cg*4;
    const int rg = tid >> 5, r0 = rg*4;
    const int sr = tid >> 3, scq = (tid & 7)*4;
    float acc[4][4];
    #pragma unroll
    for (int s=0;s<4;s++)
        #pragma unroll
        for (int u=0;u<4;u++) acc[s][u]=0.f;

    const int nk = Kd >> 5;
    for (int kk = 0; kk < nk; ++kk) {
        __syncthreads();
        *(float4*)&a_t[sr*36+scq] = *(const float4*)&A[(size_t)(row0+sr)*Kd + kk*32 + scq];
        #pragma unroll
        for (int t = 0; t < 4; ++t) {
            int f4i = tid + 256*t;
            int wr = f4i >> 5, wc = (f4i & 31)*4;
            *(float4*)&w_t[wr*128+wc] = *(const float4*)&W[(size_t)(kk*32+wr)*Nd + col0 + wc];
        }
        __syncthreads();
        #pragma unroll 8
        for (int i = 0; i < 32; ++i) {
            float av[4];
            #pragma unroll
            for (int s=0;s<4;s++) av[s] = a_t[(r0+s)*36 + i];
            float4 w4 = *(float4*)&w_t[i*128 + c0];
            float wv[4] = {w4.x, w4.y, w4.z, w4.w};
            #pragma unroll
            for (int s=0;s<4;s++)
                #pragma unroll
                for (int u=0;u<4;u++) acc[s][u] += av[s]*wv[u];
        }
    }
    #pragma unroll
    for (int s = 0; s < 4; ++s) {
        float o[4];
        #pragma unroll
        for (int u=0;u<4;u++) {
            float x = acc[s][u] + (bias ? bias[col0+c0+u] : 0.f);
            o[u] = (act == 1) ? gelu_exact(x) : x;
        }
        float4 ov = {o[0], o[1], o[2], o[3]};
        *(float4*)&out[(size_t)(row0+r0+s)*Nd + col0 + c0] = ov;
    }
}

// ---------------------------------------------------------------------------
// FFN2 GEMM with fused bias + residual + LayerNorm2 epilogue.
// ---------------------------------------------------------------------------
__global__ __launch_bounds__(256) void gemm_ln2_kernel(
    const float* __restrict__ A, const float* __restrict__ W,
    const float* __restrict__ b2, const float* __restrict__ res,
    const float* __restrict__ g, const float* __restrict__ bb,
    float* __restrict__ out)
{
    __shared__ float a_t[32*36];
    __shared__ float w_t[32*128];
    const int tid  = threadIdx.x;
    const int row0 = blockIdx.x * 32;
    const int cg = tid & 31, c0 = cg*4;
    const int rg = tid >> 5, r0 = rg*4;
    const int sr = tid >> 3, scq = (tid & 7)*4;
    float acc[4][4];
    #pragma unroll
    for (int s=0;s<4;s++)
        #pragma unroll
        for (int u=0;u<4;u++) acc[s][u]=0.f;

    for (int kk = 0; kk < 16; ++kk) {
        __syncthreads();
        *(float4*)&a_t[sr*36+scq] = *(const float4*)&A[(size_t)(row0+sr)*NF + kk*32 + scq];
        #pragma unroll
        for (int t = 0; t < 4; ++t) {
            int f4i = tid + 256*t;
            int wr = f4i >> 5, wc = (f4i & 31)*4;
            *(float4*)&w_t[wr*128+wc] = *(const float4*)&W[(size_t)(kk*32+wr)*NC + wc];
        }
        __syncthreads();
        #pragma unroll 8
        for (int i = 0; i < 32; ++i) {
            float av[4];
            #pragma unroll
            for (int s=0;s<4;s++) av[s] = a_t[(r0+s)*36 + i];
            float4 w4 = *(float4*)&w_t[i*128 + c0];
            float wv[4] = {w4.x, w4.y, w4.z, w4.w};
            #pragma unroll
            for (int s=0;s<4;s++)
                #pragma unroll
                for (int u=0;u<4;u++) acc[s][u] += av[s]*wv[u];
        }
    }
    float x[4][4];
    #pragma unroll
    for (int s=0;s<4;s++)
        #pragma unroll
        for (int u=0;u<4;u++)
            x[s][u] = acc[s][u] + b2[c0+u] + res[(size_t)(row0+r0+s)*NC + c0 + u];

    float sm[4];
    #pragma unroll
    for (int s=0;s<4;s++) sm[s] = x[s][0]+x[s][1]+x[s][2]+x[s][3];
    #pragma unroll
    for (int m = 1; m <= 16; m <<= 1)
        #pragma unroll
        for (int s=0;s<4;s++) sm[s] += __shfl_xor(sm[s], m);
    float mean[4];
    #pragma unroll
    for (int s=0;s<4;s++) mean[s] = sm[s]*(1.0f/128.0f);

    float vv[4];
    #pragma unroll
    for (int s=0;s<4;s++) {
        vv[s]=0.f;
        #pragma unroll
        for (int u=0;u<4;u++) { float d = x[s][u]-mean[s]; vv[s] += d*d; }
    }
    #pragma unroll
    for (int m = 1; m <= 16; m <<= 1)
        #pragma unroll
        for (int s=0;s<4;s++) vv[s] += __shfl_xor(vv[s], m);

    #pragma unroll
    for (int s=0;s<4;s++) {
        float rstd = rsqrtf(vv[s]*(1.0f/128.0f) + 1e-5f);
        float o[4];
        #pragma unroll
        for (int u=0;u<4;u++)
            o[u] = (x[s][u]-mean[s])*rstd*g[c0+u] + bb[c0+u];
        float4 ov = {o[0],o[1],o[2],o[3]};
        *(float4*)&out[(size_t)(row0+r0+s)*NC + c0] = ov;
    }
}

// ---------------------------------------------------------------------------
extern "C" void kernel_launch(void* const* d_in, const int* in_sizes, int n_in,
                              void* d_out, int out_size, void* d_ws, size_t ws_size,
                              hipStream_t stream)
{
    (void)in_sizes; (void)n_in; (void)out_size; (void)ws_size;
    const float* q_xyz   = (const float*)d_in[0];
    const float* q_feat  = (const float*)d_in[1];
    const float* kv_xyz  = (const float*)d_in[2];
    const float* kv_feat = (const float*)d_in[3];
    const unsigned char* kv_pad = (const unsigned char*)d_in[4];
    const float* pos_w1  = (const float*)d_in[5];
    const float* pos_b1  = (const float*)d_in[6];
    const float* pos_w2  = (const float*)d_in[7];
    const float* pos_b2  = (const float*)d_in[8];
    const float* attn_w  = (const float*)d_in[9];
    const float* attn_b  = (const float*)d_in[10];
    const float* lin_w   = (const float*)d_in[11];
    const float* lin_src_w = (const float*)d_in[12];
    const float* lin_dst_w = (const float*)d_in[13];
    const float* ln1_g   = (const float*)d_in[14];
    const float* ln1_b   = (const float*)d_in[15];
    const float* ffn_w1  = (const float*)d_in[16];
    const float* ffn_b1  = (const float*)d_in[17];
    const float* ffn_w2  = (const float*)d_in[18];
    const float* ffn_b2  = (const float*)d_in[19];
    const float* ln2_g   = (const float*)d_in[20];
    const float* ln2_b   = (const float*)d_in[21];

    float* ws    = (float*)d_ws;
    int*   idx   = (int*)d_ws;                       // MQ*8 ints
    float* vfeat = ws + 131072;                      // [MQ, 128]
    float* sfeat = vfeat + (size_t)MQ*NC;            // [MQ, 128]
    float* adst  = sfeat + (size_t)MQ*NC;            // [MQ, 128]
    float* out1  = adst  + (size_t)MQ*NC;            // [MQ, 128]
    float* Hbuf  = out1  + (size_t)MQ*NC;            // [MQ, 512]

    // grid-build scratch overlaid on Hbuf (dead until FFN1)
    float4* reorder  = (float4*)Hbuf;                // 16384 float4 (256KB)
    int* cellcnt   = (int*)(reorder + 16384);        // 8192
    int* cellfill  = cellcnt + 8192;                 // 8192
    int* cellstart = cellfill + 8192;                // 8193
    // bf16 weight images also overlaid on Hbuf (offset 512KB, dead until FFN1)
    unsigned short* wimg1 = (unsigned short*)((char*)Hbuf + 524288); // 40960B
    unsigned short* wimg2 = wimg1 + 20480;                           // 40960B

    wprep_kernel<<<dim3(64), dim3(256), 0, stream>>>(pos_w2, attn_w, wimg1, wimg2);

    grid_zero_kernel<<<dim3(64), dim3(256), 0, stream>>>(cellcnt);   // zeroes cnt+fill
    grid_count_kernel<<<dim3(64), dim3(256), 0, stream>>>(kv_xyz, kv_pad, cellcnt);
    grid_scan_kernel<<<dim3(1), dim3(1024), 0, stream>>>(cellcnt, cellstart);
    grid_scatter_kernel<<<dim3(64), dim3(256), 0, stream>>>(kv_xyz, kv_pad, cellstart, cellfill, reorder);
    radius_grid_query_kernel<<<dim3(MQ/32), dim3(256), 0, stream>>>(q_xyz, cellstart, reorder, idx);

    gemm_kernel<<<dim3(MQ/32, 1), dim3(256), 0, stream>>>(kv_feat, lin_w,     nullptr, vfeat, 128, 128, 0);
    gemm_kernel<<<dim3(MQ/32, 1), dim3(256), 0, stream>>>(kv_feat, lin_src_w, nullptr, sfeat, 128, 128, 0);
    gemm_kernel<<<dim3(MQ/32, 1), dim3(256), 0, stream>>>(q_feat,  lin_dst_w, nullptr, adst,  128, 128, 0);

    attn_mfma_kernel<<<dim3(MQ/8), dim3(256), 0, stream>>>(
        q_xyz, q_feat, kv_xyz,
        pos_w1, pos_b1, pos_b2, attn_b, ln1_g, ln1_b,
        wimg1, wimg2, idx, vfeat, sfeat, adst, out1);

    gemm_kernel<<<dim3(MQ/32, 4), dim3(256), 0, stream>>>(out1, ffn_w1, ffn_b1, Hbuf, 128, 512, 1);
    gemm_ln2_kernel<<<dim3(MQ/32, 1), dim3(256), 0, stream>>>(Hbuf, ffn_w2, ffn_b2, out1, ln2_g, ln2_b, (float*)d_out);
}

// Round 6
// 260.365 us; speedup vs baseline: 2.9207x; 1.2336x over previous
//
#include <hip/hip_runtime.h>
#include <math.h>

#define NB 2
#define NQ 8192
#define NL 8192
#define NC 128
#define NKN 8
#define NF 512
#define MQ (NB*NQ)   // 16384 rows total (both batches)

typedef __attribute__((ext_vector_type(8))) short bf16x8;
typedef __attribute__((ext_vector_type(4))) float f32x4;

__device__ __forceinline__ unsigned short f2bf_u(float f){
    unsigned u = __float_as_uint(f);
    return (unsigned short)((u + 0x7FFFu + ((u>>16)&1u)) >> 16);
}
__device__ __forceinline__ float bf2f(unsigned short s){
    return __uint_as_float(((unsigned)s) << 16);
}

// ===========================================================================
// Radius top-8 via uniform spatial grid, 16^3 cells per batch.
// ===========================================================================

__global__ __launch_bounds__(256) void grid_zero_kernel(int* __restrict__ p)
{
    int t = blockIdx.x*256 + threadIdx.x;
    p[t] = 0;
}

__device__ __forceinline__ int cell_coord(float x) {
    int c = (int)(x * 16.0f);
    return min(15, max(0, c));
}

__global__ __launch_bounds__(256) void grid_count_kernel(
    const float* __restrict__ kxyz, const unsigned char* __restrict__ pad,
    int* __restrict__ cnt)
{
    int t = blockIdx.x*256 + threadIdx.x;
    if (pad[t]) return;
    int bat = t >> 13;
    float x = kxyz[t*3+0], y = kxyz[t*3+1], z = kxyz[t*3+2];
    int cell = (cell_coord(z)*16 + cell_coord(y))*16 + cell_coord(x);
    atomicAdd(&cnt[bat*4096 + cell], 1);
}

__global__ __launch_bounds__(1024) void grid_scan_kernel(
    const int* __restrict__ cnt, int* __restrict__ cs)
{
    __shared__ int wsum[17];
    int t = threadIdx.x;
    int v[8]; int s = 0;
    #pragma unroll
    for (int k = 0; k < 8; ++k) { v[k] = s; s += cnt[t*8 + k]; }
    int lane = t & 63, w = t >> 6;
    int inc = s;
    #pragma unroll
    for (int d = 1; d < 64; d <<= 1) {
        int o = __shfl_up(inc, d);
        if (lane >= d) inc += o;
    }
    if (lane == 63) wsum[w] = inc;
    __syncthreads();
    if (t == 0) {
        int a = 0;
        for (int i = 0; i < 16; ++i) { int x = wsum[i]; wsum[i] = a; a += x; }
        wsum[16] = a;
    }
    __syncthreads();
    int base = wsum[w] + (inc - s);
    #pragma unroll
    for (int k = 0; k < 8; ++k) cs[t*8 + k] = base + v[k];
    if (t == 1023) cs[8192] = wsum[16];
}

__global__ __launch_bounds__(256) void grid_scatter_kernel(
    const float* __restrict__ kxyz, const unsigned char* __restrict__ pad,
    const int* __restrict__ cs, int* __restrict__ fill, float4* __restrict__ ro)
{
    int t = blockIdx.x*256 + threadIdx.x;
    if (pad[t]) return;
    int bat = t >> 13, i = t & 8191;
    float x = kxyz[t*3+0], y = kxyz[t*3+1], z = kxyz[t*3+2];
    int cell = bat*4096 + (cell_coord(z)*16 + cell_coord(y))*16 + cell_coord(x);
    int pos = cs[cell] + atomicAdd(&fill[cell], 1);
    ro[pos] = make_float4(x, y, z, __int_as_float(i));
}

__device__ __forceinline__ void insert8(float cd, int id, float dk[8], int ik[8]) {
    if (cd < dk[7]) {
        dk[7] = cd; ik[7] = id;
        #pragma unroll
        for (int r = 6; r >= 0; --r) {
            bool sw = dk[r+1] < dk[r];
            float td = dk[r]; int ti = ik[r];
            dk[r]   = sw ? dk[r+1] : dk[r];
            ik[r]   = sw ? ik[r+1] : ik[r];
            dk[r+1] = sw ? td : dk[r+1];
            ik[r+1] = sw ? ti : ik[r+1];
        }
    }
}

template<int W>
__device__ __forceinline__ void scan_block(int l, int cx, int cy, int cz,
    float qx, float qy, float qz, const int* __restrict__ CS,
    const float4* __restrict__ RO, float dk[8], int ik[8])
{
    const int D = 2*W + 1;
    int xs = max(0, cx - W), xe = min(15, cx + W);
    int nx = xe - xs + 1;
    for (int r = l; r < D*D; r += 8) {
        int dz = r / D - W, dy = r % D - W;
        int zz = cz + dz, yy = cy + dy;
        if ((unsigned)zz > 15u || (unsigned)yy > 15u) continue;
        int c0 = (zz*16 + yy)*16 + xs;
        int s = CS[c0], e = CS[c0 + nx];
        for (int p = s; p < e; ++p) {
            float4 v = RO[p];
            float dx = qx - v.x, dyv = qy - v.y, dzv = qz - v.z;
            float cd = dx*dx + dyv*dyv + dzv*dzv;
            insert8(cd, __float_as_int(v.w), dk, ik);
        }
    }
}

__device__ __forceinline__ void merge8(float dk[8], int ik[8]) {
    #pragma unroll
    for (int m = 1; m <= 4; m <<= 1) {
        float od[8]; int oi[8];
        #pragma unroll
        for (int r = 0; r < 8; ++r) {
            od[r] = __shfl_xor(dk[r], m);
            oi[r] = __shfl_xor(ik[r], m);
        }
        float nd[8]; int ni[8];
        #pragma unroll
        for (int r = 0; r < 8; ++r) {
            bool take = od[7-r] < dk[r];
            nd[r] = take ? od[7-r] : dk[r];
            ni[r] = take ? oi[7-r] : ik[r];
        }
        #pragma unroll
        for (int st = 4; st >= 1; st >>= 1) {
            #pragma unroll
            for (int r = 0; r < 8; ++r) {
                if ((r & st) == 0 && (r | st) < 8) {
                    int b = r | st;
                    bool sw = nd[b] < nd[r];
                    float td = nd[r]; int ti = ni[r];
                    nd[r] = sw ? nd[b] : nd[r];
                    ni[r] = sw ? ni[b] : ni[r];
                    nd[b] = sw ? td : nd[b];
                    ni[b] = sw ? ti : ni[b];
                }
            }
        }
        #pragma unroll
        for (int r = 0; r < 8; ++r) { dk[r] = nd[r]; ik[r] = ni[r]; }
    }
}

__global__ __launch_bounds__(256) void radius_grid_query_kernel(
    const float* __restrict__ qxyz, const int* __restrict__ cellstart,
    const float4* __restrict__ reorder, int* __restrict__ idxout)
{
    const int tid  = threadIdx.x;
    const int l    = tid & 7;
    const int qloc = tid >> 3;
    const int gq   = blockIdx.x*32 + qloc;
    const int bat  = gq >> 13;
    const float qx = qxyz[gq*3+0], qy = qxyz[gq*3+1], qz = qxyz[gq*3+2];
    const int cx = cell_coord(qx), cy = cell_coord(qy), cz = cell_coord(qz);
    const int* CS = cellstart + bat*4096;
    const float R2  = (float)(0.4*0.4);
    const float R2P = __uint_as_float(__float_as_uint(R2) + 1u);

    float dk[8]; int ik[8];
    #pragma unroll
    for (int r = 0; r < 8; ++r) { dk[r] = R2P; ik[r] = -1; }

    scan_block<2>(l, cx, cy, cz, qx, qy, qz, CS, reorder, dk, ik);
    merge8(dk, ik);
    bool done = dk[7] <= 0.015625f;

    if (!done) {
        #pragma unroll
        for (int r = 0; r < 8; ++r) { dk[r] = R2P; ik[r] = -1; }
        scan_block<4>(l, cx, cy, cz, qx, qy, qz, CS, reorder, dk, ik);
        merge8(dk, ik);
        done = dk[7] <= 0.0625f;
    }
    if (!done) {
        #pragma unroll
        for (int r = 0; r < 8; ++r) { dk[r] = R2P; ik[r] = -1; }
        scan_block<16>(l, cx, cy, cz, qx, qy, qz, CS, reorder, dk, ik);
        merge8(dk, ik);
    }

    if (l == 0) {
        int o[8];
        #pragma unroll
        for (int r = 0; r < 8; ++r) o[r] = (dk[r] <= R2) ? ik[r] : -1;
        int4 a = {o[0], o[1], o[2], o[3]};
        int4 b = {o[4], o[5], o[6], o[7]};
        *(int4*)&idxout[(size_t)gq*8 + 0] = a;
        *(int4*)&idxout[(size_t)gq*8 + 4] = b;
    }
}

// ===========================================================================
// Weight prep kernels.
// wprep_kernel (attn path): 80B-row image, as in round 5.
// wprep2_kernel (dense GEMMs): img[((k>>5)*Nd + n)*32 + (k&31)] = bf16(W[k][n])
// -> 64B-row [col][k_local] chunk images for direct int4 LDS copy.
// ===========================================================================
__global__ __launch_bounds__(256) void wprep_kernel(
    const float* __restrict__ wA, const float* __restrict__ wB,
    unsigned short* __restrict__ imgA, unsigned short* __restrict__ imgB)
{
    int t = blockIdx.x*256 + threadIdx.x;   // 16384 = 128x128
    int k = t >> 7, c = t & 127;
    int off = (k >> 5)*5120 + c*40 + (k & 31);
    imgA[off] = f2bf_u(wA[t]);
    imgB[off] = f2bf_u(wB[t]);
}

__global__ __launch_bounds__(256) void wprep2_kernel(
    const float* __restrict__ W, unsigned short* __restrict__ img, int lgN)
{
    int t = blockIdx.x*256 + threadIdx.x;
    int k = t >> lgN, n = t & ((1 << lgN) - 1);
    int Nd = 1 << lgN;
    img[(((k >> 5)*Nd + n) << 5) + (k & 31)] = f2bf_u(W[t]);
}

// ===========================================================================
// Generic bf16-MFMA GEMM: out[M,Nd] = act(A[M,Kd]@W + bias)
// 256 thr = 4 waves; block tile 64 rows x 128 cols; wave = 16 rows x 128 cols.
// A fp32 -> bf16 converted during LDS staging ([row][32k], 64B stride).
// B from pre-formatted global image (straight int4 copy).
// ACT: 0 none, 1 exact gelu.  OUTBF: write bf16 instead of fp32.
// ===========================================================================
__device__ inline float gelu_exact(float x) {
    return 0.5f*x*(1.0f + erff(x*0.7071067811865476f));
}

template<int ACT, bool OUTBF>
__global__ __launch_bounds__(256) void gemm_mfma(
    const float* __restrict__ A, const unsigned short* __restrict__ Bimg,
    const float* __restrict__ bias, void* __restrict__ outv,
    int Kd, int Nd)
{
    __shared__ unsigned short sA[64*32];    // 4KB
    __shared__ unsigned short sB[128*32];   // 8KB
    const int tid = threadIdx.x;
    const int w = tid >> 6, lane = tid & 63, l15 = lane & 15, quad = lane >> 4;
    const int row0 = blockIdx.x*64, col0 = blockIdx.y*128;

    f32x4 acc[8];
    #pragma unroll
    for (int t=0;t<8;t++){ acc[t][0]=0.f; acc[t][1]=0.f; acc[t][2]=0.f; acc[t][3]=0.f; }

    const int nch = Kd >> 5;
    for (int kc = 0; kc < nch; ++kc) {
        __syncthreads();
        #pragma unroll
        for (int it = 0; it < 2; ++it) {
            int idx = it*256 + tid;          // 0..511: r(64) x kq(8)
            int r = idx >> 3, kq = idx & 7;
            float4 a4 = *(const float4*)&A[(size_t)(row0+r)*Kd + kc*32 + kq*4];
            ushort4 pk = { f2bf_u(a4.x), f2bf_u(a4.y), f2bf_u(a4.z), f2bf_u(a4.w) };
            *(ushort4*)&sA[r*32 + kq*4] = pk;
        }
        const int4* bsrc = (const int4*)(Bimg + ((size_t)kc*Nd + col0)*32);
        #pragma unroll
        for (int it = 0; it < 2; ++it) {
            int o = it*256 + tid;
            ((int4*)sB)[o] = bsrc[o];
        }
        __syncthreads();
        bf16x8 af = *(const bf16x8*)&sA[(w*16 + l15)*32 + quad*8];
        #pragma unroll
        for (int t = 0; t < 8; ++t) {
            bf16x8 bf = *(const bf16x8*)&sB[(16*t + l15)*32 + quad*8];
            acc[t] = __builtin_amdgcn_mfma_f32_16x16x32_bf16(af, bf, acc[t], 0, 0, 0);
        }
    }

    const int rowb = row0 + w*16 + quad*4;
    #pragma unroll
    for (int t = 0; t < 8; ++t) {
        int col = col0 + 16*t + l15;
        float bv = bias ? bias[col] : 0.f;
        #pragma unroll
        for (int r = 0; r < 4; ++r) {
            float x = acc[t][r] + bv;
            if (ACT == 1) x = gelu_exact(x);
            if (OUTBF) ((unsigned short*)outv)[(size_t)(rowb+r)*Nd + col] = f2bf_u(x);
            else       ((float*)outv)[(size_t)(rowb+r)*Nd + col] = x;
        }
    }
}

// ===========================================================================
// FFN2 + residual + LN2, bf16-MFMA. A = Hbuf bf16 [M][512], B = ffn_w2 image.
// Block 64 rows x 128 cols (full N); LN per row in C-layout (sum over 8
// t-frags + shfl_xor 1/2/4/8 across the 16 lanes sharing the row).
// ===========================================================================
__global__ __launch_bounds__(256) void gemm2_ln_mfma(
    const unsigned short* __restrict__ Abf, const unsigned short* __restrict__ Bimg,
    const float* __restrict__ b2, const float* __restrict__ res,
    const float* __restrict__ g, const float* __restrict__ bb,
    float* __restrict__ out)
{
    __shared__ unsigned short sA[64*32];
    __shared__ unsigned short sB[128*32];
    const int tid = threadIdx.x;
    const int w = tid >> 6, lane = tid & 63, l15 = lane & 15, quad = lane >> 4;
    const int row0 = blockIdx.x*64;

    f32x4 acc[8];
    #pragma unroll
    for (int t=0;t<8;t++){ acc[t][0]=0.f; acc[t][1]=0.f; acc[t][2]=0.f; acc[t][3]=0.f; }

    for (int kc = 0; kc < 16; ++kc) {
        __syncthreads();
        {   // A: 64 rows x 32 bf16 = 256 int4, 1 iter
            int r = tid >> 2, kq = tid & 3;
            ((int4*)sA)[tid] = *(const int4*)&Abf[(size_t)(row0+r)*NF + kc*32 + kq*8];
        }
        const int4* bsrc = (const int4*)(Bimg + (size_t)kc*NC*32);
        #pragma unroll
        for (int it = 0; it < 2; ++it) {
            int o = it*256 + tid;
            ((int4*)sB)[o] = bsrc[o];
        }
        __syncthreads();
        bf16x8 af = *(const bf16x8*)&sA[(w*16 + l15)*32 + quad*8];
        #pragma unroll
        for (int t = 0; t < 8; ++t) {
            bf16x8 bf = *(const bf16x8*)&sB[(16*t + l15)*32 + quad*8];
            acc[t] = __builtin_amdgcn_mfma_f32_16x16x32_bf16(af, bf, acc[t], 0, 0, 0);
        }
    }

    const int rowb = row0 + w*16 + quad*4;
    #pragma unroll
    for (int r = 0; r < 4; ++r) {
        int row = rowb + r;
        float xv[8]; float S = 0.f;
        #pragma unroll
        for (int t = 0; t < 8; ++t) {
            int col = 16*t + l15;
            xv[t] = acc[t][r] + b2[col] + res[(size_t)row*NC + col];
            S += xv[t];
        }
        #pragma unroll
        for (int m = 1; m <= 8; m <<= 1) S += __shfl_xor(S, m);
        float mean = S * (1.f/128.f);
        float V = 0.f;
        #pragma unroll
        for (int t = 0; t < 8; ++t) { float d = xv[t]-mean; V += d*d; }
        #pragma unroll
        for (int m = 1; m <= 8; m <<= 1) V += __shfl_xor(V, m);
        float rstd = rsqrtf(V*(1.f/128.f) + 1e-5f);
        #pragma unroll
        for (int t = 0; t < 8; ++t) {
            int col = 16*t + l15;
            out[(size_t)row*NC + col] = (xv[t]-mean)*rstd*g[col] + bb[col];
        }
    }
}

// ===========================================================================
// Fused per-edge attention via bf16 MFMA (round-5 structure; vfeat/sfeat bf16).
// ===========================================================================
__global__ __launch_bounds__(256) void attn_mfma_kernel(
    const float* __restrict__ qxyz, const float* __restrict__ qfeat,
    const float* __restrict__ kxyz,
    const float* __restrict__ posw1, const float* __restrict__ posb1,
    const float* __restrict__ posb2, const float* __restrict__ attnb,
    const float* __restrict__ ln1g, const float* __restrict__ ln1b,
    const unsigned short* __restrict__ wimg1, const unsigned short* __restrict__ wimg2,
    const int* __restrict__ idx, const unsigned short* __restrict__ vfeat,
    const unsigned short* __restrict__ sfeat, const float* __restrict__ adst,
    float* __restrict__ out1)
{
    __shared__ int4 s_wc[640];
    __shared__ int4 s_t4[1088];
    __shared__ float s_w1[384];
    __shared__ float s_b1[128], s_b2[128], s_ab[128], s_g[128], s_bb[128];
    __shared__ int   s_j[64];

    const int tid  = threadIdx.x;
    const int w    = tid >> 6;
    const int lane = tid & 63;
    const int l15  = lane & 15;
    const int quad = lane >> 4;
    const int qbase = blockIdx.x*8 + w*2;
    const int bat  = (blockIdx.x*8) >> 13;

    if (tid < 128) {
        s_b1[tid] = posb1[tid]; s_b2[tid] = posb2[tid];
        s_ab[tid] = attnb[tid]; s_g[tid] = ln1g[tid]; s_bb[tid] = ln1b[tid];
    } else {
        int i = tid - 128;
        s_w1[i] = posw1[i]; s_w1[128+i] = posw1[128+i]; s_w1[256+i] = posw1[256+i];
    }
    if (tid < 64) s_j[tid] = idx[(size_t)blockIdx.x*64 + tid];
    __syncthreads();

    bf16x8 h1f[4];
    {
        int e  = w*16 + l15;
        int qh = qbase + (l15 >> 3);
        int j  = s_j[e];
        int jc = j < 0 ? 0 : j;
        const float* kp = kxyz + ((size_t)(bat*NL + jc))*3;
        float rx = qxyz[qh*3+0]-kp[0], ry = qxyz[qh*3+1]-kp[1], rz = qxyz[qh*3+2]-kp[2];
        #pragma unroll
        for (int kk=0;kk<4;kk++){
            #pragma unroll
            for (int jj=0;jj<8;jj++){
                int c = kk*32 + quad*8 + jj;
                float h = s_b1[c] + rx*s_w1[c] + ry*s_w1[128+c] + rz*s_w1[256+c];
                h = fmaxf(h, 0.f);
                h1f[kk][jj] = (short)f2bf_u(h);
            }
        }
    }

    f32x4 acc[8];
    #pragma unroll
    for (int t=0;t<8;t++){ acc[t][0]=0.f; acc[t][1]=0.f; acc[t][2]=0.f; acc[t][3]=0.f; }

    for (int kk=0;kk<4;kk++){
        __syncthreads();
        const int4* src = (const int4*)(wimg1 + (size_t)kk*5120);
        #pragma unroll
        for (int r=0;r<3;r++){
            int o = r*256 + tid;
            if (o < 640) s_wc[o] = src[o];
        }
        __syncthreads();
        const char* wb = (const char*)s_wc;
        #pragma unroll
        for (int t=0;t<8;t++){
            bf16x8 wf = *(const bf16x8*)(wb + (16*t + l15)*80 + quad*16);
            acc[t] = __builtin_amdgcn_mfma_f32_16x16x32_bf16(h1f[kk], wf, acc[t], 0, 0, 0);
        }
    }

    f32x4 dreg[8];
    #pragma unroll
    for (int t=0;t<8;t++){
        float b2v = s_b2[16*t + l15];
        #pragma unroll
        for (int r=0;r<4;r++) dreg[t][r] = fmaxf(acc[t][r] + b2v, 0.f);
    }

    int jr[4]; bool val[4];
    #pragma unroll
    for (int r=0;r<4;r++){
        int j = s_j[w*16 + quad*4 + r];
        val[r] = (j >= 0); jr[r] = j < 0 ? 0 : j;
    }
    const int qt = qbase + (quad >> 1);
    char* st = (char*)s_t4 + w*4352;
    #pragma unroll
    for (int t=0;t<8;t++){
        float ad = adst[(size_t)qt*NC + 16*t + l15];
        #pragma unroll
        for (int r=0;r<4;r++){
            float sv = bf2f(sfeat[((size_t)(bat*NL + jr[r]))*NC + 16*t + l15]);
            float tv = ad - sv + dreg[t][r];
            *(unsigned short*)(st + (quad*4+r)*272 + (16*t+l15)*2) = f2bf_u(tv);
        }
    }

    f32x4 acc2[8];
    #pragma unroll
    for (int t=0;t<8;t++){ acc2[t][0]=0.f; acc2[t][1]=0.f; acc2[t][2]=0.f; acc2[t][3]=0.f; }

    for (int kk=0;kk<4;kk++){
        __syncthreads();
        const int4* src = (const int4*)(wimg2 + (size_t)kk*5120);
        #pragma unroll
        for (int r=0;r<3;r++){
            int o = r*256 + tid;
            if (o < 640) s_wc[o] = src[o];
        }
        __syncthreads();
        bf16x8 tf = *(const bf16x8*)(st + l15*272 + kk*64 + quad*16);
        const char* wb = (const char*)s_wc;
        #pragma unroll
        for (int t=0;t<8;t++){
            bf16x8 wf = *(const bf16x8*)(wb + (16*t + l15)*80 + quad*16);
            acc2[t] = __builtin_amdgcn_mfma_f32_16x16x32_bf16(tf, wf, acc2[t], 0, 0, 0);
        }
    }

    float ex[8][4]; float dnm[8];
    #pragma unroll
    for (int t=0;t<8;t++){
        float ab = s_ab[16*t + l15];
        float s0 = val[0] ? fmaxf(acc2[t][0] + ab, 0.f) : -INFINITY;
        float s1 = val[1] ? fmaxf(acc2[t][1] + ab, 0.f) : -INFINITY;
        float s2 = val[2] ? fmaxf(acc2[t][2] + ab, 0.f) : -INFINITY;
        float s3 = val[3] ? fmaxf(acc2[t][3] + ab, 0.f) : -INFINITY;
        float mx = fmaxf(fmaxf(s0,s1), fmaxf(s2,s3));
        mx = fmaxf(mx, __shfl_xor(mx, 16));
        if (mx < -1e37f) mx = 0.f;
        ex[t][0] = __expf(s0 - mx);
        ex[t][1] = __expf(s1 - mx);
        ex[t][2] = __expf(s2 - mx);
        ex[t][3] = __expf(s3 - mx);
        float sm = ex[t][0]+ex[t][1]+ex[t][2]+ex[t][3];
        sm += __shfl_xor(sm, 16);
        dnm[t] = fmaxf(sm, 1e-12f);
    }

    float part[8];
    #pragma unroll
    for (int t=0;t<8;t++){
        float p = 0.f;
        #pragma unroll
        for (int r=0;r<4;r++){
            float vv = bf2f(vfeat[((size_t)(bat*NL + jr[r]))*NC + 16*t + l15]);
            p += ex[t][r] * (vv + dreg[t][r]);
        }
        p += __shfl_xor(p, 16);
        part[t] = p / dnm[t];
    }

    float xln[8];
    float S = 0.f;
    #pragma unroll
    for (int t=0;t<8;t++){
        xln[t] = qfeat[(size_t)qt*NC + 16*t + l15] + part[t];
        S += xln[t];
    }
    #pragma unroll
    for (int m=1;m<=8;m<<=1) S += __shfl_xor(S, m);
    float mean = S * (1.f/128.f);
    float V = 0.f;
    #pragma unroll
    for (int t=0;t<8;t++){ float d = xln[t]-mean; V += d*d; }
    #pragma unroll
    for (int m=1;m<=8;m<<=1) V += __shfl_xor(V, m);
    float rstd = rsqrtf(V*(1.f/128.f) + 1e-5f);

    if ((quad & 1) == 0){
        #pragma unroll
        for (int t=0;t<8;t++){
            int c = 16*t + l15;
            out1[(size_t)qt*NC + c] = (xln[t]-mean)*rstd*s_g[c] + s_bb[c];
        }
    }
}

// ---------------------------------------------------------------------------
extern "C" void kernel_launch(void* const* d_in, const int* in_sizes, int n_in,
                              void* d_out, int out_size, void* d_ws, size_t ws_size,
                              hipStream_t stream)
{
    (void)in_sizes; (void)n_in; (void)out_size; (void)ws_size;
    const float* q_xyz   = (const float*)d_in[0];
    const float* q_feat  = (const float*)d_in[1];
    const float* kv_xyz  = (const float*)d_in[2];
    const float* kv_feat = (const float*)d_in[3];
    const unsigned char* kv_pad = (const unsigned char*)d_in[4];
    const float* pos_w1  = (const float*)d_in[5];
    const float* pos_b1  = (const float*)d_in[6];
    const float* pos_w2  = (const float*)d_in[7];
    const float* pos_b2  = (const float*)d_in[8];
    const float* attn_w  = (const float*)d_in[9];
    const float* attn_b  = (const float*)d_in[10];
    const float* lin_w   = (const float*)d_in[11];
    const float* lin_src_w = (const float*)d_in[12];
    const float* lin_dst_w = (const float*)d_in[13];
    const float* ln1_g   = (const float*)d_in[14];
    const float* ln1_b   = (const float*)d_in[15];
    const float* ffn_w1  = (const float*)d_in[16];
    const float* ffn_b1  = (const float*)d_in[17];
    const float* ffn_w2  = (const float*)d_in[18];
    const float* ffn_b2  = (const float*)d_in[19];
    const float* ln2_g   = (const float*)d_in[20];
    const float* ln2_b   = (const float*)d_in[21];

    float* ws    = (float*)d_ws;
    int*   idx   = (int*)d_ws;                                 // MQ*8 ints
    unsigned short* vfeat = (unsigned short*)(ws + 131072);    // [MQ,128] bf16
    unsigned short* sfeat = (unsigned short*)(ws + 131072 + 2097152);
    float* adst  = ws + 131072 + 2*2097152;                    // [MQ,128] fp32
    float* out1  = adst + 2097152;                             // [MQ,128] fp32
    float* Hreg  = out1 + 2097152;                             // old Hbuf fp32 region (33.5MB)
    unsigned short* Hbuf = (unsigned short*)Hreg;              // [MQ,512] bf16 (16.8MB)

    // grid-build scratch at Hreg start: used pre-attn, clobbered later by Hbuf
    float4* reorder  = (float4*)Hreg;                // 256KB
    int* cellcnt   = (int*)(reorder + 16384);        // 8192
    int* cellfill  = cellcnt + 8192;                 // 8192
    int* cellstart = cellfill + 8192;                // 8193

    // weight images at Hreg + 18MB (beyond Hbuf-bf16 extent, within fp32 slot)
    unsigned short* imgb = (unsigned short*)((char*)Hreg + 18u*1024*1024);
    unsigned short* wimg1 = imgb;             // pos_w2 (attn layout, 20480)
    unsigned short* wimg2 = imgb + 20480;     // attn_w (attn layout, 20480)
    unsigned short* wv    = imgb + 40960;     // lin_w      (16384)
    unsigned short* wsr   = imgb + 57344;     // lin_src_w  (16384)
    unsigned short* wd    = imgb + 73728;     // lin_dst_w  (16384)
    unsigned short* wf1   = imgb + 90112;     // ffn_w1     (65536)
    unsigned short* wf2   = imgb + 155648;    // ffn_w2     (65536)

    wprep_kernel<<<dim3(64), dim3(256), 0, stream>>>(pos_w2, attn_w, wimg1, wimg2);
    wprep2_kernel<<<dim3(64),  dim3(256), 0, stream>>>(lin_w,     wv,  7);
    wprep2_kernel<<<dim3(64),  dim3(256), 0, stream>>>(lin_src_w, wsr, 7);
    wprep2_kernel<<<dim3(64),  dim3(256), 0, stream>>>(lin_dst_w, wd,  7);
    wprep2_kernel<<<dim3(256), dim3(256), 0, stream>>>(ffn_w1,    wf1, 9);
    wprep2_kernel<<<dim3(256), dim3(256), 0, stream>>>(ffn_w2,    wf2, 7);

    grid_zero_kernel<<<dim3(64), dim3(256), 0, stream>>>(cellcnt);
    grid_count_kernel<<<dim3(64), dim3(256), 0, stream>>>(kv_xyz, kv_pad, cellcnt);
    grid_scan_kernel<<<dim3(1), dim3(1024), 0, stream>>>(cellcnt, cellstart);
    grid_scatter_kernel<<<dim3(64), dim3(256), 0, stream>>>(kv_xyz, kv_pad, cellstart, cellfill, reorder);
    radius_grid_query_kernel<<<dim3(MQ/32), dim3(256), 0, stream>>>(q_xyz, cellstart, reorder, idx);

    gemm_mfma<0,true ><<<dim3(MQ/64,1), dim3(256), 0, stream>>>(kv_feat, wv,  nullptr, vfeat, 128, 128);
    gemm_mfma<0,true ><<<dim3(MQ/64,1), dim3(256), 0, stream>>>(kv_feat, wsr, nullptr, sfeat, 128, 128);
    gemm_mfma<0,false><<<dim3(MQ/64,1), dim3(256), 0, stream>>>(q_feat,  wd,  nullptr, adst,  128, 128);

    attn_mfma_kernel<<<dim3(MQ/8), dim3(256), 0, stream>>>(
        q_xyz, q_feat, kv_xyz,
        pos_w1, pos_b1, pos_b2, attn_b, ln1_g, ln1_b,
        wimg1, wimg2, idx, vfeat, sfeat, adst, out1);

    gemm_mfma<1,true ><<<dim3(MQ/64,4), dim3(256), 0, stream>>>(out1, wf1, ffn_b1, Hbuf, 128, 512);
    gemm2_ln_mfma<<<dim3(MQ/64), dim3(256), 0, stream>>>(Hbuf, wf2, ffn_b2, out1, ln2_g, ln2_b, (float*)d_out);
}

// Round 7
// 234.162 us; speedup vs baseline: 3.2475x; 1.1119x over previous
//
#include <hip/hip_runtime.h>
#include <math.h>

#define NB 2
#define NQ 8192
#define NL 8192
#define NC 128
#define NKN 8
#define NF 512
#define MQ (NB*NQ)   // 16384 rows total (both batches)

typedef __attribute__((ext_vector_type(8))) short bf16x8;
typedef __attribute__((ext_vector_type(4))) float f32x4;

__device__ __forceinline__ unsigned short f2bf_u(float f){
    unsigned u = __float_as_uint(f);
    return (unsigned short)((u + 0x7FFFu + ((u>>16)&1u)) >> 16);
}
__device__ __forceinline__ float bf2f(unsigned short s){
    return __uint_as_float(((unsigned)s) << 16);
}

// ===========================================================================
// Radius top-8 via uniform spatial grid, 16^3 cells per batch.
// ===========================================================================

__global__ __launch_bounds__(256) void grid_zero_kernel(int* __restrict__ p)
{
    int t = blockIdx.x*256 + threadIdx.x;
    p[t] = 0;
}

__device__ __forceinline__ int cell_coord(float x) {
    int c = (int)(x * 16.0f);
    return min(15, max(0, c));
}

__global__ __launch_bounds__(256) void grid_count_kernel(
    const float* __restrict__ kxyz, const unsigned char* __restrict__ pad,
    int* __restrict__ cnt)
{
    int t = blockIdx.x*256 + threadIdx.x;
    if (pad[t]) return;
    int bat = t >> 13;
    float x = kxyz[t*3+0], y = kxyz[t*3+1], z = kxyz[t*3+2];
    int cell = (cell_coord(z)*16 + cell_coord(y))*16 + cell_coord(x);
    atomicAdd(&cnt[bat*4096 + cell], 1);
}

__global__ __launch_bounds__(1024) void grid_scan_kernel(
    const int* __restrict__ cnt, int* __restrict__ cs)
{
    __shared__ int wsum[17];
    int t = threadIdx.x;
    int v[8]; int s = 0;
    #pragma unroll
    for (int k = 0; k < 8; ++k) { v[k] = s; s += cnt[t*8 + k]; }
    int lane = t & 63, w = t >> 6;
    int inc = s;
    #pragma unroll
    for (int d = 1; d < 64; d <<= 1) {
        int o = __shfl_up(inc, d);
        if (lane >= d) inc += o;
    }
    if (lane == 63) wsum[w] = inc;
    __syncthreads();
    if (t == 0) {
        int a = 0;
        for (int i = 0; i < 16; ++i) { int x = wsum[i]; wsum[i] = a; a += x; }
        wsum[16] = a;
    }
    __syncthreads();
    int base = wsum[w] + (inc - s);
    #pragma unroll
    for (int k = 0; k < 8; ++k) cs[t*8 + k] = base + v[k];
    if (t == 1023) cs[8192] = wsum[16];
}

__global__ __launch_bounds__(256) void grid_scatter_kernel(
    const float* __restrict__ kxyz, const unsigned char* __restrict__ pad,
    const int* __restrict__ cs, int* __restrict__ fill, float4* __restrict__ ro)
{
    int t = blockIdx.x*256 + threadIdx.x;
    if (pad[t]) return;
    int bat = t >> 13, i = t & 8191;
    float x = kxyz[t*3+0], y = kxyz[t*3+1], z = kxyz[t*3+2];
    int cell = bat*4096 + (cell_coord(z)*16 + cell_coord(y))*16 + cell_coord(x);
    int pos = cs[cell] + atomicAdd(&fill[cell], 1);
    ro[pos] = make_float4(x, y, z, __int_as_float(i));
}

__device__ __forceinline__ void insert8(float cd, int id, float dk[8], int ik[8]) {
    if (cd < dk[7]) {
        dk[7] = cd; ik[7] = id;
        #pragma unroll
        for (int r = 6; r >= 0; --r) {
            bool sw = dk[r+1] < dk[r];
            float td = dk[r]; int ti = ik[r];
            dk[r]   = sw ? dk[r+1] : dk[r];
            ik[r]   = sw ? ik[r+1] : ik[r];
            dk[r+1] = sw ? td : dk[r+1];
            ik[r+1] = sw ? ti : ik[r+1];
        }
    }
}

template<int W>
__device__ __forceinline__ void scan_block(int l, int cx, int cy, int cz,
    float qx, float qy, float qz, const int* __restrict__ CS,
    const float4* __restrict__ RO, float dk[8], int ik[8])
{
    const int D = 2*W + 1;
    int xs = max(0, cx - W), xe = min(15, cx + W);
    int nx = xe - xs + 1;
    for (int r = l; r < D*D; r += 8) {
        int dz = r / D - W, dy = r % D - W;
        int zz = cz + dz, yy = cy + dy;
        if ((unsigned)zz > 15u || (unsigned)yy > 15u) continue;
        int c0 = (zz*16 + yy)*16 + xs;
        int s = CS[c0], e = CS[c0 + nx];
        for (int p = s; p < e; ++p) {
            float4 v = RO[p];
            float dx = qx - v.x, dyv = qy - v.y, dzv = qz - v.z;
            float cd = dx*dx + dyv*dyv + dzv*dzv;
            insert8(cd, __float_as_int(v.w), dk, ik);
        }
    }
}

__device__ __forceinline__ void merge8(float dk[8], int ik[8]) {
    #pragma unroll
    for (int m = 1; m <= 4; m <<= 1) {
        float od[8]; int oi[8];
        #pragma unroll
        for (int r = 0; r < 8; ++r) {
            od[r] = __shfl_xor(dk[r], m);
            oi[r] = __shfl_xor(ik[r], m);
        }
        float nd[8]; int ni[8];
        #pragma unroll
        for (int r = 0; r < 8; ++r) {
            bool take = od[7-r] < dk[r];
            nd[r] = take ? od[7-r] : dk[r];
            ni[r] = take ? oi[7-r] : ik[r];
        }
        #pragma unroll
        for (int st = 4; st >= 1; st >>= 1) {
            #pragma unroll
            for (int r = 0; r < 8; ++r) {
                if ((r & st) == 0 && (r | st) < 8) {
                    int b = r | st;
                    bool sw = nd[b] < nd[r];
                    float td = nd[r]; int ti = ni[r];
                    nd[r] = sw ? nd[b] : nd[r];
                    ni[r] = sw ? ni[b] : ni[r];
                    nd[b] = sw ? td : nd[b];
                    ni[b] = sw ? ti : ni[b];
                }
            }
        }
        #pragma unroll
        for (int r = 0; r < 8; ++r) { dk[r] = nd[r]; ik[r] = ni[r]; }
    }
}

__global__ __launch_bounds__(256) void radius_grid_query_kernel(
    const float* __restrict__ qxyz, const int* __restrict__ cellstart,
    const float4* __restrict__ reorder, int* __restrict__ idxout)
{
    const int tid  = threadIdx.x;
    const int l    = tid & 7;
    const int qloc = tid >> 3;
    const int gq   = blockIdx.x*32 + qloc;
    const int bat  = gq >> 13;
    const float qx = qxyz[gq*3+0], qy = qxyz[gq*3+1], qz = qxyz[gq*3+2];
    const int cx = cell_coord(qx), cy = cell_coord(qy), cz = cell_coord(qz);
    const int* CS = cellstart + bat*4096;
    const float R2  = (float)(0.4*0.4);
    const float R2P = __uint_as_float(__float_as_uint(R2) + 1u);

    float dk[8]; int ik[8];
    #pragma unroll
    for (int r = 0; r < 8; ++r) { dk[r] = R2P; ik[r] = -1; }

    scan_block<2>(l, cx, cy, cz, qx, qy, qz, CS, reorder, dk, ik);
    merge8(dk, ik);
    bool done = dk[7] <= 0.015625f;

    if (!done) {
        #pragma unroll
        for (int r = 0; r < 8; ++r) { dk[r] = R2P; ik[r] = -1; }
        scan_block<4>(l, cx, cy, cz, qx, qy, qz, CS, reorder, dk, ik);
        merge8(dk, ik);
        done = dk[7] <= 0.0625f;
    }
    if (!done) {
        #pragma unroll
        for (int r = 0; r < 8; ++r) { dk[r] = R2P; ik[r] = -1; }
        scan_block<16>(l, cx, cy, cz, qx, qy, qz, CS, reorder, dk, ik);
        merge8(dk, ik);
    }

    if (l == 0) {
        int o[8];
        #pragma unroll
        for (int r = 0; r < 8; ++r) o[r] = (dk[r] <= R2) ? ik[r] : -1;
        int4 a = {o[0], o[1], o[2], o[3]};
        int4 b = {o[4], o[5], o[6], o[7]};
        *(int4*)&idxout[(size_t)gq*8 + 0] = a;
        *(int4*)&idxout[(size_t)gq*8 + 4] = b;
    }
}

// ===========================================================================
// Unified weight prep: all images dense [chunk kk][col n][k&31] bf16,
// chunk stride Nd*32 ushorts, row (col) stride 32 ushorts (64B, 2-way banks).
// imgb ushort offsets: wimg1 0, wimg2 16384, wvs 32768 (Nd=256),
// wd 65536, wf1 81920 (Nd=512), wf2 147456.
// Grid: 832 x 256 = 212992 threads exactly.
// ===========================================================================
__global__ __launch_bounds__(256) void prep_all_kernel(
    const float* __restrict__ posw2, const float* __restrict__ attnw,
    const float* __restrict__ lin_w, const float* __restrict__ lin_src_w,
    const float* __restrict__ lin_dst_w,
    const float* __restrict__ ffn_w1, const float* __restrict__ ffn_w2,
    unsigned short* __restrict__ imgb)
{
    int t = blockIdx.x*256 + threadIdx.x;
    if (t < 16384) {
        int k = t >> 7, n = t & 127;
        imgb[(k >> 5)*4096 + n*32 + (k & 31)] = f2bf_u(posw2[t]);
    } else if (t < 32768) {
        int u = t - 16384;
        int k = u >> 7, n = u & 127;
        imgb[16384 + (k >> 5)*4096 + n*32 + (k & 31)] = f2bf_u(attnw[u]);
    } else if (t < 65536) {
        int u = t - 32768;
        int k = u >> 8, n = u & 255;
        float v = (n < 128) ? lin_w[k*128 + n] : lin_src_w[k*128 + (n-128)];
        imgb[32768 + ((k >> 5)*256 + n)*32 + (k & 31)] = f2bf_u(v);
    } else if (t < 81920) {
        int u = t - 65536;
        int k = u >> 7, n = u & 127;
        imgb[65536 + ((k >> 5)*128 + n)*32 + (k & 31)] = f2bf_u(lin_dst_w[u]);
    } else if (t < 147456) {
        int u = t - 81920;
        int k = u >> 9, n = u & 511;
        imgb[81920 + ((k >> 5)*512 + n)*32 + (k & 31)] = f2bf_u(ffn_w1[u]);
    } else {
        int u = t - 147456;
        int k = u >> 7, n = u & 127;
        imgb[147456 + ((k >> 5)*128 + n)*32 + (k & 31)] = f2bf_u(ffn_w2[u]);
    }
}

// ===========================================================================
// Generic bf16-MFMA GEMM: out[M,Nd] = act(A[M,Kd]@W + bias)
// ===========================================================================
__device__ inline float gelu_exact(float x) {
    return 0.5f*x*(1.0f + erff(x*0.7071067811865476f));
}

template<int ACT, bool OUTBF>
__global__ __launch_bounds__(256) void gemm_mfma(
    const float* __restrict__ A, const unsigned short* __restrict__ Bimg,
    const float* __restrict__ bias, void* __restrict__ outv,
    int Kd, int Nd)
{
    __shared__ unsigned short sA[64*32];    // 4KB
    __shared__ unsigned short sB[128*32];   // 8KB
    const int tid = threadIdx.x;
    const int w = tid >> 6, lane = tid & 63, l15 = lane & 15, quad = lane >> 4;
    const int row0 = blockIdx.x*64, col0 = blockIdx.y*128;

    f32x4 acc[8];
    #pragma unroll
    for (int t=0;t<8;t++){ acc[t][0]=0.f; acc[t][1]=0.f; acc[t][2]=0.f; acc[t][3]=0.f; }

    const int nch = Kd >> 5;
    for (int kc = 0; kc < nch; ++kc) {
        __syncthreads();
        #pragma unroll
        for (int it = 0; it < 2; ++it) {
            int idx = it*256 + tid;          // 0..511: r(64) x kq(8)
            int r = idx >> 3, kq = idx & 7;
            float4 a4 = *(const float4*)&A[(size_t)(row0+r)*Kd + kc*32 + kq*4];
            ushort4 pk = { f2bf_u(a4.x), f2bf_u(a4.y), f2bf_u(a4.z), f2bf_u(a4.w) };
            *(ushort4*)&sA[r*32 + kq*4] = pk;
        }
        const int4* bsrc = (const int4*)(Bimg + ((size_t)kc*Nd + col0)*32);
        #pragma unroll
        for (int it = 0; it < 2; ++it) {
            int o = it*256 + tid;
            ((int4*)sB)[o] = bsrc[o];
        }
        __syncthreads();
        bf16x8 af = *(const bf16x8*)&sA[(w*16 + l15)*32 + quad*8];
        #pragma unroll
        for (int t = 0; t < 8; ++t) {
            bf16x8 bf = *(const bf16x8*)&sB[(16*t + l15)*32 + quad*8];
            acc[t] = __builtin_amdgcn_mfma_f32_16x16x32_bf16(af, bf, acc[t], 0, 0, 0);
        }
    }

    const int rowb = row0 + w*16 + quad*4;
    #pragma unroll
    for (int t = 0; t < 8; ++t) {
        int col = col0 + 16*t + l15;
        float bv = bias ? bias[col] : 0.f;
        #pragma unroll
        for (int r = 0; r < 4; ++r) {
            float x = acc[t][r] + bv;
            if (ACT == 1) x = gelu_exact(x);
            if (OUTBF) ((unsigned short*)outv)[(size_t)(rowb+r)*Nd + col] = f2bf_u(x);
            else       ((float*)outv)[(size_t)(rowb+r)*Nd + col] = x;
        }
    }
}

// ===========================================================================
// FFN2 + residual + LN2, bf16-MFMA.
// ===========================================================================
__global__ __launch_bounds__(256) void gemm2_ln_mfma(
    const unsigned short* __restrict__ Abf, const unsigned short* __restrict__ Bimg,
    const float* __restrict__ b2, const float* __restrict__ res,
    const float* __restrict__ g, const float* __restrict__ bb,
    float* __restrict__ out)
{
    __shared__ unsigned short sA[64*32];
    __shared__ unsigned short sB[128*32];
    const int tid = threadIdx.x;
    const int w = tid >> 6, lane = tid & 63, l15 = lane & 15, quad = lane >> 4;
    const int row0 = blockIdx.x*64;

    f32x4 acc[8];
    #pragma unroll
    for (int t=0;t<8;t++){ acc[t][0]=0.f; acc[t][1]=0.f; acc[t][2]=0.f; acc[t][3]=0.f; }

    for (int kc = 0; kc < 16; ++kc) {
        __syncthreads();
        {
            int r = tid >> 2, kq = tid & 3;
            ((int4*)sA)[tid] = *(const int4*)&Abf[(size_t)(row0+r)*NF + kc*32 + kq*8];
        }
        const int4* bsrc = (const int4*)(Bimg + (size_t)kc*NC*32);
        #pragma unroll
        for (int it = 0; it < 2; ++it) {
            int o = it*256 + tid;
            ((int4*)sB)[o] = bsrc[o];
        }
        __syncthreads();
        bf16x8 af = *(const bf16x8*)&sA[(w*16 + l15)*32 + quad*8];
        #pragma unroll
        for (int t = 0; t < 8; ++t) {
            bf16x8 bf = *(const bf16x8*)&sB[(16*t + l15)*32 + quad*8];
            acc[t] = __builtin_amdgcn_mfma_f32_16x16x32_bf16(af, bf, acc[t], 0, 0, 0);
        }
    }

    const int rowb = row0 + w*16 + quad*4;
    #pragma unroll
    for (int r = 0; r < 4; ++r) {
        int row = rowb + r;
        float xv[8]; float S = 0.f;
        #pragma unroll
        for (int t = 0; t < 8; ++t) {
            int col = 16*t + l15;
            xv[t] = acc[t][r] + b2[col] + res[(size_t)row*NC + col];
            S += xv[t];
        }
        #pragma unroll
        for (int m = 1; m <= 8; m <<= 1) S += __shfl_xor(S, m);
        float mean = S * (1.f/128.f);
        float V = 0.f;
        #pragma unroll
        for (int t = 0; t < 8; ++t) { float d = xv[t]-mean; V += d*d; }
        #pragma unroll
        for (int m = 1; m <= 8; m <<= 1) V += __shfl_xor(V, m);
        float rstd = rsqrtf(V*(1.f/128.f) + 1e-5f);
        #pragma unroll
        for (int t = 0; t < 8; ++t) {
            int col = 16*t + l15;
            out[(size_t)row*NC + col] = (xv[t]-mean)*rstd*g[col] + bb[col];
        }
    }
}

// ===========================================================================
// Fused per-edge attention v2.
// - whole weight images staged to 32KB LDS (wimg1, overwritten by wimg2) -> 3 barriers
// - per-wave vectorized staging of gathered v|s rows ([row][256] vs tensor)
// - T built in-place over the staged s tile
// ===========================================================================
__global__ __launch_bounds__(256) void attn_mfma_kernel(
    const float* __restrict__ qxyz, const float* __restrict__ qfeat,
    const float* __restrict__ kxyz,
    const float* __restrict__ posw1, const float* __restrict__ posb1,
    const float* __restrict__ posb2, const float* __restrict__ attnb,
    const float* __restrict__ ln1g, const float* __restrict__ ln1b,
    const unsigned short* __restrict__ wimg1, const unsigned short* __restrict__ wimg2,
    const int* __restrict__ idx, const unsigned short* __restrict__ vs,
    const float* __restrict__ adst, float* __restrict__ out1)
{
    __shared__ unsigned short s_w[16384];      // 32KB weight image
    __shared__ unsigned short s_V[4*16*136];   // 17408B v-rows (per-wave 16x136)
    __shared__ unsigned short s_T[4*16*136];   // s-rows, then T in-place
    __shared__ float s_w1[384];
    __shared__ float s_b1[128], s_b2[128], s_ab[128], s_g[128], s_bb[128];
    __shared__ int   s_j[64];

    const int tid  = threadIdx.x;
    const int w    = tid >> 6;
    const int lane = tid & 63;
    const int l15  = lane & 15;
    const int quad = lane >> 4;
    const int qbase = blockIdx.x*8 + w*2;
    const int bat  = (blockIdx.x*8) >> 13;

    if (tid < 128) {
        s_b1[tid] = posb1[tid]; s_b2[tid] = posb2[tid];
        s_ab[tid] = attnb[tid]; s_g[tid] = ln1g[tid]; s_bb[tid] = ln1b[tid];
    } else {
        int i = tid - 128;
        s_w1[i] = posw1[i]; s_w1[128+i] = posw1[128+i]; s_w1[256+i] = posw1[256+i];
    }
    if (tid < 64) s_j[tid] = idx[(size_t)blockIdx.x*64 + tid];
    #pragma unroll
    for (int r = 0; r < 8; ++r)
        ((int4*)s_w)[r*256 + tid] = ((const int4*)wimg1)[r*256 + tid];
    __syncthreads();                           // sync0

    // --- per-wave vectorized staging of v|s rows for this wave's 16 edges ---
    #pragma unroll
    for (int i = 0; i < 4; ++i) {
        int ix = lane + i*64;                  // 0..255: e(16) x c16(16)
        int el = ix >> 4, c16 = ix & 15;
        int j = s_j[w*16 + el];
        int jc = j < 0 ? 0 : j;
        const int4* rp = (const int4*)(vs + ((size_t)(bat*NL + jc))*256);
        int dst = (w*16 + el)*136 + c16*8;     // ushort idx, 16B aligned
        *(int4*)&s_V[dst] = rp[c16];           // v half (cols 0..127)
        *(int4*)&s_T[dst] = rp[16 + c16];      // s half (cols 128..255)
    }

    // --- h1 A-fragments ---
    bf16x8 h1f[4];
    {
        int e  = w*16 + l15;
        int qh = qbase + (l15 >> 3);
        int j  = s_j[e];
        int jc = j < 0 ? 0 : j;
        const float* kp = kxyz + ((size_t)(bat*NL + jc))*3;
        float rx = qxyz[qh*3+0]-kp[0], ry = qxyz[qh*3+1]-kp[1], rz = qxyz[qh*3+2]-kp[2];
        #pragma unroll
        for (int kk=0;kk<4;kk++){
            #pragma unroll
            for (int jj=0;jj<8;jj++){
                int c = kk*32 + quad*8 + jj;
                float h = s_b1[c] + rx*s_w1[c] + ry*s_w1[128+c] + rz*s_w1[256+c];
                h = fmaxf(h, 0.f);
                h1f[kk][jj] = (short)f2bf_u(h);
            }
        }
    }

    // --- GEMM1 (no barriers: weights fully resident) ---
    f32x4 acc[8];
    #pragma unroll
    for (int t=0;t<8;t++){ acc[t][0]=0.f; acc[t][1]=0.f; acc[t][2]=0.f; acc[t][3]=0.f; }
    #pragma unroll
    for (int kk=0;kk<4;kk++){
        #pragma unroll
        for (int t=0;t<8;t++){
            bf16x8 wf = *(const bf16x8*)&s_w[kk*4096 + (16*t + l15)*32 + quad*8];
            acc[t] = __builtin_amdgcn_mfma_f32_16x16x32_bf16(h1f[kk], wf, acc[t], 0, 0, 0);
        }
    }

    f32x4 dreg[8];
    #pragma unroll
    for (int t=0;t<8;t++){
        float b2v = s_b2[16*t + l15];
        #pragma unroll
        for (int r=0;r<4;r++) dreg[t][r] = fmaxf(acc[t][r] + b2v, 0.f);
    }

    int jr[4]; bool val[4];
    #pragma unroll
    for (int r=0;r<4;r++){
        int j = s_j[w*16 + quad*4 + r];
        val[r] = (j >= 0); jr[r] = j < 0 ? 0 : j;
    }
    const int qt = qbase + (quad >> 1);
    float ad[8];
    #pragma unroll
    for (int t=0;t<8;t++) ad[t] = adst[(size_t)qt*NC + 16*t + l15];

    __syncthreads();                           // sync1: GEMM1 done, V/S visible

    // stage wimg2 over s_w (overlaps with T build)
    #pragma unroll
    for (int r = 0; r < 8; ++r)
        ((int4*)s_w)[r*256 + tid] = ((const int4*)wimg2)[r*256 + tid];

    // --- T = adst - s + delta, in-place over staged s tile (C-layout lanes) ---
    {
        unsigned short* st = s_T + w*16*136;
        #pragma unroll
        for (int t=0;t<8;t++){
            #pragma unroll
            for (int r=0;r<4;r++){
                int o = (quad*4 + r)*136 + 16*t + l15;
                float sv = bf2f(st[o]);
                st[o] = f2bf_u(ad[t] - sv + dreg[t][r]);
            }
        }
    }
    __syncthreads();                           // sync2: T + wimg2 ready

    // --- GEMM2 (no barriers) ---
    f32x4 acc2[8];
    #pragma unroll
    for (int t=0;t<8;t++){ acc2[t][0]=0.f; acc2[t][1]=0.f; acc2[t][2]=0.f; acc2[t][3]=0.f; }
    {
        const unsigned short* st = s_T + w*16*136;
        #pragma unroll
        for (int kk=0;kk<4;kk++){
            bf16x8 tf = *(const bf16x8*)&st[l15*136 + kk*32 + quad*8];
            #pragma unroll
            for (int t=0;t<8;t++){
                bf16x8 wf = *(const bf16x8*)&s_w[kk*4096 + (16*t + l15)*32 + quad*8];
                acc2[t] = __builtin_amdgcn_mfma_f32_16x16x32_bf16(tf, wf, acc2[t], 0, 0, 0);
            }
        }
    }

    // --- softmax over the 8 edges of each query, per channel ---
    float ex[8][4]; float dnm[8];
    #pragma unroll
    for (int t=0;t<8;t++){
        float ab = s_ab[16*t + l15];
        float s0 = val[0] ? fmaxf(acc2[t][0] + ab, 0.f) : -INFINITY;
        float s1 = val[1] ? fmaxf(acc2[t][1] + ab, 0.f) : -INFINITY;
        float s2 = val[2] ? fmaxf(acc2[t][2] + ab, 0.f) : -INFINITY;
        float s3 = val[3] ? fmaxf(acc2[t][3] + ab, 0.f) : -INFINITY;
        float mx = fmaxf(fmaxf(s0,s1), fmaxf(s2,s3));
        mx = fmaxf(mx, __shfl_xor(mx, 16));
        if (mx < -1e37f) mx = 0.f;
        ex[t][0] = __expf(s0 - mx);
        ex[t][1] = __expf(s1 - mx);
        ex[t][2] = __expf(s2 - mx);
        ex[t][3] = __expf(s3 - mx);
        float sm = ex[t][0]+ex[t][1]+ex[t][2]+ex[t][3];
        sm += __shfl_xor(sm, 16);
        dnm[t] = fmaxf(sm, 1e-12f);
    }

    // --- agg from staged V tile ---
    float part[8];
    #pragma unroll
    for (int t=0;t<8;t++){
        float p = 0.f;
        #pragma unroll
        for (int r=0;r<4;r++){
            float vv = bf2f(s_V[(w*16 + quad*4 + r)*136 + 16*t + l15]);
            p += ex[t][r] * (vv + dreg[t][r]);
        }
        p += __shfl_xor(p, 16);
        part[t] = p / dnm[t];
    }

    // --- residual + LN1 ---
    float xln[8];
    float S = 0.f;
    #pragma unroll
    for (int t=0;t<8;t++){
        xln[t] = qfeat[(size_t)qt*NC + 16*t + l15] + part[t];
        S += xln[t];
    }
    #pragma unroll
    for (int m=1;m<=8;m<<=1) S += __shfl_xor(S, m);
    float mean = S * (1.f/128.f);
    float V = 0.f;
    #pragma unroll
    for (int t=0;t<8;t++){ float d = xln[t]-mean; V += d*d; }
    #pragma unroll
    for (int m=1;m<=8;m<<=1) V += __shfl_xor(V, m);
    float rstd = rsqrtf(V*(1.f/128.f) + 1e-5f);

    if ((quad & 1) == 0){
        #pragma unroll
        for (int t=0;t<8;t++){
            int c = 16*t + l15;
            out1[(size_t)qt*NC + c] = (xln[t]-mean)*rstd*s_g[c] + s_bb[c];
        }
    }
}

// ---------------------------------------------------------------------------
extern "C" void kernel_launch(void* const* d_in, const int* in_sizes, int n_in,
                              void* d_out, int out_size, void* d_ws, size_t ws_size,
                              hipStream_t stream)
{
    (void)in_sizes; (void)n_in; (void)out_size; (void)ws_size;
    const float* q_xyz   = (const float*)d_in[0];
    const float* q_feat  = (const float*)d_in[1];
    const float* kv_xyz  = (const float*)d_in[2];
    const float* kv_feat = (const float*)d_in[3];
    const unsigned char* kv_pad = (const unsigned char*)d_in[4];
    const float* pos_w1  = (const float*)d_in[5];
    const float* pos_b1  = (const float*)d_in[6];
    const float* pos_w2  = (const float*)d_in[7];
    const float* pos_b2  = (const float*)d_in[8];
    const float* attn_w  = (const float*)d_in[9];
    const float* attn_b  = (const float*)d_in[10];
    const float* lin_w   = (const float*)d_in[11];
    const float* lin_src_w = (const float*)d_in[12];
    const float* lin_dst_w = (const float*)d_in[13];
    const float* ln1_g   = (const float*)d_in[14];
    const float* ln1_b   = (const float*)d_in[15];
    const float* ffn_w1  = (const float*)d_in[16];
    const float* ffn_b1  = (const float*)d_in[17];
    const float* ffn_w2  = (const float*)d_in[18];
    const float* ffn_b2  = (const float*)d_in[19];
    const float* ln2_g   = (const float*)d_in[20];
    const float* ln2_b   = (const float*)d_in[21];

    float* ws    = (float*)d_ws;
    int*   idx   = (int*)d_ws;                                 // MQ*8 ints
    unsigned short* vs = (unsigned short*)(ws + 131072);       // [MQ,256] bf16 (v|s)
    float* adst  = ws + 131072 + 2*2097152;                    // [MQ,128] fp32
    float* out1  = adst + 2097152;                             // [MQ,128] fp32
    float* Hreg  = out1 + 2097152;                             // fp32-Hbuf-sized region
    unsigned short* Hbuf = (unsigned short*)Hreg;              // [MQ,512] bf16 (16.8MB)

    // grid-build scratch at Hreg start: used pre-attn, clobbered later by Hbuf
    float4* reorder  = (float4*)Hreg;                // 256KB
    int* cellcnt   = (int*)(reorder + 16384);        // 8192
    int* cellfill  = cellcnt + 8192;                 // 8192
    int* cellstart = cellfill + 8192;                // 8193

    // weight images at Hreg + 18MB (beyond Hbuf-bf16 extent)
    unsigned short* imgb  = (unsigned short*)((char*)Hreg + 18u*1024*1024);
    unsigned short* wimg1 = imgb;             // pos_w2    (16384)
    unsigned short* wimg2 = imgb + 16384;     // attn_w    (16384)
    unsigned short* wvs   = imgb + 32768;     // lin_w|lin_src_w (32768, Nd=256)
    unsigned short* wd    = imgb + 65536;     // lin_dst_w (16384)
    unsigned short* wf1   = imgb + 81920;     // ffn_w1    (65536, Nd=512)
    unsigned short* wf2   = imgb + 147456;    // ffn_w2    (65536)

    prep_all_kernel<<<dim3(832), dim3(256), 0, stream>>>(
        pos_w2, attn_w, lin_w, lin_src_w, lin_dst_w, ffn_w1, ffn_w2, imgb);

    grid_zero_kernel<<<dim3(64), dim3(256), 0, stream>>>(cellcnt);
    grid_count_kernel<<<dim3(64), dim3(256), 0, stream>>>(kv_xyz, kv_pad, cellcnt);
    grid_scan_kernel<<<dim3(1), dim3(1024), 0, stream>>>(cellcnt, cellstart);
    grid_scatter_kernel<<<dim3(64), dim3(256), 0, stream>>>(kv_xyz, kv_pad, cellstart, cellfill, reorder);
    radius_grid_query_kernel<<<dim3(MQ/32), dim3(256), 0, stream>>>(q_xyz, cellstart, reorder, idx);

    gemm_mfma<0,true ><<<dim3(MQ/64,2), dim3(256), 0, stream>>>(kv_feat, wvs, nullptr, vs,   128, 256);
    gemm_mfma<0,false><<<dim3(MQ/64,1), dim3(256), 0, stream>>>(q_feat,  wd,  nullptr, adst, 128, 128);

    attn_mfma_kernel<<<dim3(MQ/8), dim3(256), 0, stream>>>(
        q_xyz, q_feat, kv_xyz,
        pos_w1, pos_b1, pos_b2, attn_b, ln1_g, ln1_b,
        wimg1, wimg2, idx, vs, adst, out1);

    gemm_mfma<1,true ><<<dim3(MQ/64,4), dim3(256), 0, stream>>>(out1, wf1, ffn_b1, Hbuf, 128, 512);
    gemm2_ln_mfma<<<dim3(MQ/64), dim3(256), 0, stream>>>(Hbuf, wf2, ffn_b2, out1, ln2_g, ln2_b, (float*)d_out);
}